// Round 8
// baseline (641.569 us; speedup 1.0000x reference)
//
#include <hip/hip_runtime.h>

#define B_ 4
#define S_ 4096
#define D_ 1024

typedef __bf16 bf16;
typedef _Float16 f16;
typedef __attribute__((ext_vector_type(8))) __bf16 bf16x8;
typedef __attribute__((ext_vector_type(8))) _Float16 f16x8;
typedef __attribute__((ext_vector_type(4))) float floatx4;
typedef __attribute__((ext_vector_type(16))) float floatx16;

__device__ inline floatx4 mfma16(bf16x8 a, bf16x8 b, floatx4 c) {
    return __builtin_amdgcn_mfma_f32_16x16x32_bf16(a, b, c, 0, 0, 0);
}
__device__ inline floatx4 mfma_any(bf16x8 a, bf16x8 b, floatx4 c) {
    return __builtin_amdgcn_mfma_f32_16x16x32_bf16(a, b, c, 0, 0, 0);
}
__device__ inline floatx4 mfma_any(f16x8 a, f16x8 b, floatx4 c) {
    return __builtin_amdgcn_mfma_f32_16x16x32_f16(a, b, c, 0, 0, 0);
}
// 32x32x16 variants: A/B = 8 elems/lane, C/D = 16 f32/lane.
__device__ inline floatx16 mfma_any(bf16x8 a, bf16x8 b, floatx16 c) {
    return __builtin_amdgcn_mfma_f32_32x32x16_bf16(a, b, c, 0, 0, 0);
}
__device__ inline floatx16 mfma_any(f16x8 a, f16x8 b, floatx16 c) {
    return __builtin_amdgcn_mfma_f32_32x32x16_f16(a, b, c, 0, 0, 0);
}

template <typename T> struct vec8_of;
template <> struct vec8_of<bf16> { using type = bf16x8; };
template <> struct vec8_of<f16>  { using type = f16x8; };

__device__ inline bf16x8 cvt8(float4 a, float4 b) {
    bf16x8 h;
    h[0] = (bf16)a.x; h[1] = (bf16)a.y; h[2] = (bf16)a.z; h[3] = (bf16)a.w;
    h[4] = (bf16)b.x; h[5] = (bf16)b.y; h[6] = (bf16)b.z; h[7] = (bf16)b.w;
    return h;
}

// ---------------------------------------------------------------------------
// elementwise fp32 -> bf16 cast (n multiple of 2048)
// ---------------------------------------------------------------------------
__global__ __launch_bounds__(256) void cast_f32_bf16(
    const float* __restrict__ in, bf16* __restrict__ out)
{
    size_t i = ((size_t)blockIdx.x * 256 + threadIdx.x) * 8;
    float4 a = *(const float4*)(in + i);
    float4 b = *(const float4*)(in + i + 4);
    *(bf16x8*)(out + i) = cvt8(a, b);
}

// ---------------------------------------------------------------------------
// gemm256 v7 = round-7 32x32x16 kernel with FRAGMENT-MAJOR LDS layout.
// Round-7 post-mortem: row-major LDS + (row&7)<<4 XOR swizzle (verified
// conflict-free for the 16x16 read pattern) produced 1.26e7 bank conflicts
// with the 32x32 read (32 rows x 32B window per read). Fix: store each
// half-tile in fragment order [f = i*4+ks][lane][16B], so every ds_read is
// base + lane*16 -- lane-linear, conflict-free BY CONSTRUCTION, no XOR.
// The permutation lives entirely in the global source of global_load_lds
// (LDS dest stays linear, as required): chunk idx -> f=idx>>6, l=idx&63,
// row=(f>>2)*32+(l&31), col=(f&3)*16+(l>>5)*8. Same formula serves A and B
// ((f>>3)*64+((f>>2)&1)*32 == (f>>2)*32). Lane's read of frag (i,ks) yields
// X[i*32+l32][ks*16+kg*8+j] -- the exact layout round 7 verified.
// Everything else identical to round 7: 4 phases/K-tile, stage A(t+1)h1@P1,
// B(t+2)h0@P3, B(t+2)h1+A(t+2)h0@P4, single vmcnt(6)/tile (3 half-tiles in
// flight), compile-time buffer parity, patch-major+XCD tile order, setprio.
// ---------------------------------------------------------------------------
template <typename TI, typename TO, bool HAS_BIAS>
__global__ __launch_bounds__(512, 2) void gemm256(
    const TI* __restrict__ A, const TI* __restrict__ B, TO* __restrict__ C,
    int K, int ldc, size_t strideA, size_t strideB, size_t strideC,
    const float* __restrict__ bias1, const float* __restrict__ bias2,
    float scale, int tiles_n)
{
    using v8 = typename vec8_of<TI>::type;
    __shared__ __align__(16) TI sA[2][2][8192];
    __shared__ __align__(16) TI sB[2][2][8192];

    A += (size_t)blockIdx.z * strideA;
    B += (size_t)blockIdx.z * strideB;
    C += (size_t)blockIdx.z * strideC;

    const int tid = threadIdx.x;
    const int wave = tid >> 6, lane = tid & 63;
    const int l32 = lane & 31, kg = lane >> 5;
    const int wm = wave >> 2, wn = wave & 3;

    // XCD-bijective chunking + 4x4 patch-major tile order
    const int gx = gridDim.x;
    const int cpx = gx >> 3;
    const int lid = (blockIdx.x & 7) * cpx + (blockIdx.x >> 3);
    const int p = lid >> 4, w = lid & 15;
    const int pr = tiles_n >> 2;
    const int Pm = p / pr, Pn = p - Pm * pr;
    const int tm = Pm * 4 + (w >> 2), tn = Pn * 4 + (w & 3);
    const int m0 = tm * 256, n0 = tn * 256;

    const TI* Abase = A + (size_t)m0 * K;
    const TI* Bbase = B + (size_t)n0 * K;

    // staging source map: chunk idx (16B) -> fragment-major position.
    size_t goff[2];
#pragma unroll
    for (int j = 0; j < 2; j++) {
        int idx = j * 512 + tid;
        int f = idx >> 6, l = idx & 63;
        int r = (f >> 2) * 32 + (l & 31);
        int c = (f & 3) * 16 + ((l >> 5) & 1) * 8;
        goff[j] = (size_t)r * K + c;
    }
    const int NT = K >> 6;
    const size_t halfA = (size_t)128 * K;

    auto stageA = [&](int t, int half, int bufsel) {
#pragma unroll
        for (int j = 0; j < 2; j++) {
            int idx = j * 512 + tid;
            __builtin_amdgcn_global_load_lds(
                (const __attribute__((address_space(1))) void*)(
                    Abase + (size_t)t * 64 + (half ? halfA : 0) + goff[j]),
                (__attribute__((address_space(3))) void*)(sA[bufsel][half] + idx * 8),
                16, 0, 0);
        }
    };
    auto stageB = [&](int t, int half, int bufsel) {
#pragma unroll
        for (int j = 0; j < 2; j++) {
            int idx = j * 512 + tid;
            __builtin_amdgcn_global_load_lds(
                (const __attribute__((address_space(1))) void*)(
                    Bbase + (size_t)t * 64 + (half ? halfA : 0) + goff[j]),
                (__attribute__((address_space(3))) void*)(sB[bufsel][half] + idx * 8),
                16, 0, 0);
        }
    };
    // fragment reads: lane-linear, conflict-free. A-half = wm; B-half = wn>>1;
    // B window within half = wn&1.
    auto rdA = [&](int buf, int i, int ks) -> v8 {
        return *(const v8*)(sA[buf][wm] + (i * 4 + ks) * 512 + lane * 8);
    };
    auto rdB = [&](int buf, int j, int ks) -> v8 {
        return *(const v8*)(sB[buf][wn >> 1] + (((wn & 1) * 2 + j) * 4 + ks) * 512 + lane * 8);
    };

    floatx16 acc[4][2];
#pragma unroll
    for (int i = 0; i < 4; i++)
#pragma unroll
        for (int j = 0; j < 2; j++) acc[i][j] = (floatx16)0.0f;

    // prologue: tile0 (4 half-tiles) + B(1)h0,h1 + A(1)h0; vmcnt(6).
    {
        int t1 = (1 < NT) ? 1 : 0;
        stageA(0, 0, 0); stageA(0, 1, 0);
        stageB(0, 0, 0); stageB(0, 1, 0);
        stageB(t1, 0, 1); stageB(t1, 1, 1);
        stageA(t1, 0, 1);
        asm volatile("s_waitcnt vmcnt(6)" ::: "memory");
        __builtin_amdgcn_s_barrier();
    }

    v8 a[8], b0[4], b1[4];
    for (int u = 0; u < NT; u += 2) {
#pragma unroll
        for (int half_it = 0; half_it < 2; half_it++) {
            const int t = u + half_it;
            const int buf = half_it;                        // compile-time
            const int tA = (t + 1 < NT) ? t + 1 : NT - 1;
            const int tB = (t + 2 < NT) ? t + 2 : NT - 1;

            // ---- P1: Q11 m01 x n0 ; reads a01(8) + b0(4) ; stage A(t+1)h1 ----
#pragma unroll
            for (int i = 0; i < 2; i++)
#pragma unroll
                for (int ks = 0; ks < 4; ks++) a[i * 4 + ks] = rdA(buf, i, ks);
#pragma unroll
            for (int ks = 0; ks < 4; ks++) b0[ks] = rdB(buf, 0, ks);
            stageA(tA, 1, buf ^ 1);
            __builtin_amdgcn_s_barrier();
            __builtin_amdgcn_s_setprio(1);
#pragma unroll
            for (int i = 0; i < 2; i++)
#pragma unroll
                for (int ks = 0; ks < 4; ks++)
                    acc[i][0] = mfma_any(a[i * 4 + ks], b0[ks], acc[i][0]);
            __builtin_amdgcn_s_setprio(0);
            __builtin_amdgcn_s_barrier();

            // ---- P2: Q12 m01 x n1 ; reads b1(4) ----
#pragma unroll
            for (int ks = 0; ks < 4; ks++) b1[ks] = rdB(buf, 1, ks);
            __builtin_amdgcn_s_barrier();
            __builtin_amdgcn_s_setprio(1);
#pragma unroll
            for (int i = 0; i < 2; i++)
#pragma unroll
                for (int ks = 0; ks < 4; ks++)
                    acc[i][1] = mfma_any(a[i * 4 + ks], b1[ks], acc[i][1]);
            __builtin_amdgcn_s_setprio(0);
            __builtin_amdgcn_s_barrier();

            // ---- P3: Q22 m23 x n1 ; reads a23(8) ; stage B(t+2)h0 ----
#pragma unroll
            for (int i = 0; i < 2; i++)
#pragma unroll
                for (int ks = 0; ks < 4; ks++) a[i * 4 + ks] = rdA(buf, 2 + i, ks);
            stageB(tB, 0, buf);
            __builtin_amdgcn_s_barrier();
            __builtin_amdgcn_s_setprio(1);
#pragma unroll
            for (int i = 0; i < 2; i++)
#pragma unroll
                for (int ks = 0; ks < 4; ks++)
                    acc[2 + i][1] = mfma_any(a[i * 4 + ks], b1[ks], acc[2 + i][1]);
            __builtin_amdgcn_s_setprio(0);
            __builtin_amdgcn_s_barrier();

            // ---- P4: Q21 m23 x n0 ; stage B(t+2)h1 + A(t+2)h0 ; vmcnt(6) ----
            stageB(tB, 1, buf);
            stageA(tB, 0, buf);
            asm volatile("s_waitcnt vmcnt(6)" ::: "memory");
            __builtin_amdgcn_s_barrier();
            __builtin_amdgcn_s_setprio(1);
#pragma unroll
            for (int i = 0; i < 2; i++)
#pragma unroll
                for (int ks = 0; ks < 4; ks++)
                    acc[2 + i][0] = mfma_any(a[i * 4 + ks], b0[ks], acc[2 + i][0]);
            __builtin_amdgcn_s_setprio(0);
            __builtin_amdgcn_s_barrier();
        }
    }

    // epilogue: col=lane&31, row=(reg&3)+8*(reg>>2)+4*(lane>>5)
#pragma unroll
    for (int mf = 0; mf < 4; mf++)
#pragma unroll
        for (int nf = 0; nf < 2; nf++) {
            int col = n0 + wn * 64 + nf * 32 + l32;
            float badd = 0.0f;
            if (HAS_BIAS) {
                badd = bias1[col];
                if (bias2) badd += bias2[col];
            }
#pragma unroll
            for (int r = 0; r < 16; r++) {
                int row = m0 + wm * 128 + mf * 32 + (r & 3) + 8 * (r >> 2) + 4 * kg;
                float v = acc[mf][nf][r];
                if (HAS_BIAS) v = (v + badd) * scale;
                C[(size_t)row * ldc + col] = (TO)v;
            }
        }
}

// ---------------------------------------------------------------------------
// m97-style GEMM (kept for fallback paths)
// ---------------------------------------------------------------------------
template <typename TI, typename TO, bool HAS_BIAS>
__global__ __launch_bounds__(256) void gemm128(
    const TI* __restrict__ A, const TI* __restrict__ B, TO* __restrict__ C,
    int K, int ldc, size_t strideA, size_t strideB, size_t strideC,
    const float* __restrict__ bias1, const float* __restrict__ bias2, float scale)
{
    using v8 = typename vec8_of<TI>::type;
    __shared__ TI sA[2 * 128 * 32];
    __shared__ TI sB[2 * 128 * 32];
    A += (size_t)blockIdx.z * strideA;
    B += (size_t)blockIdx.z * strideB;
    C += (size_t)blockIdx.z * strideC;

    const int tid = threadIdx.x;
    const int wave = tid >> 6, lane = tid & 63, quad = lane >> 4, l16 = lane & 15;
    const int m0 = blockIdx.x * 128, n0 = blockIdx.y * 128;
    const int wr = (wave >> 1) * 64, wc = (wave & 1) * 64;

    floatx4 acc[4][4];
#pragma unroll
    for (int i = 0; i < 4; i++)
#pragma unroll
        for (int j = 0; j < 4; j++) acc[i][j] = (floatx4)0.0f;

    for (int k0 = 0; k0 < K; k0 += 64) {
#pragma unroll
        for (int s = 0; s < 2; s++) {
#pragma unroll
            for (int j = 0; j < 2; j++) {
                int idx = j * 256 + tid;
                int r = idx >> 2, c = (idx & 3) * 8;
                __builtin_amdgcn_global_load_lds(
                    (const __attribute__((address_space(1))) void*)(A + (size_t)(m0 + r) * K + k0 + s * 32 + c),
                    (__attribute__((address_space(3))) void*)(sA + s * 4096 + idx * 8), 16, 0, 0);
                __builtin_amdgcn_global_load_lds(
                    (const __attribute__((address_space(1))) void*)(B + (size_t)(n0 + r) * K + k0 + s * 32 + c),
                    (__attribute__((address_space(3))) void*)(sB + s * 4096 + idx * 8), 16, 0, 0);
            }
        }
        __syncthreads();
#pragma unroll
        for (int s = 0; s < 2; s++) {
            v8 af[4], bfv[4];
#pragma unroll
            for (int i = 0; i < 4; i++) {
                af[i]  = *(const v8*)&sA[s * 4096 + (wr + i * 16 + l16) * 32 + quad * 8];
                bfv[i] = *(const v8*)&sB[s * 4096 + (wc + i * 16 + l16) * 32 + quad * 8];
            }
#pragma unroll
            for (int mf = 0; mf < 4; mf++)
#pragma unroll
                for (int nf = 0; nf < 4; nf++)
                    acc[mf][nf] = mfma_any(af[mf], bfv[nf], acc[mf][nf]);
        }
        __syncthreads();
    }

#pragma unroll
    for (int mf = 0; mf < 4; mf++)
#pragma unroll
        for (int nf = 0; nf < 4; nf++) {
            int col = n0 + wc + nf * 16 + l16;
            float badd = 0.0f;
            if (HAS_BIAS) {
                badd = bias1[col];
                if (bias2) badd += bias2[col];
            }
#pragma unroll
            for (int r = 0; r < 4; r++) {
                int row = m0 + wr + mf * 16 + quad * 4 + r;
                float v = acc[mf][nf][r];
                if (HAS_BIAS) v = (v + badd) * scale;
                C[(size_t)row * ldc + col] = (TO)v;
            }
        }
}

// ---------------------------------------------------------------------------
// transposes: vb [b][s][d] -> vtb [b][d][s]
// ---------------------------------------------------------------------------
__global__ __launch_bounds__(256) void transpose_v(
    const bf16* __restrict__ vb, bf16* __restrict__ vtb)
{
    __shared__ bf16 tile[32][33];
    const int b = blockIdx.z;
    const int s0 = blockIdx.x * 32, d0 = blockIdx.y * 32;
    const int tr = threadIdx.x >> 5;
    const int tc = threadIdx.x & 31;
#pragma unroll
    for (int k = 0; k < 4; k++) {
        int r = tr + k * 8;
        tile[r][tc] = vb[((size_t)b * S_ + s0 + r) * D_ + d0 + tc];
    }
    __syncthreads();
#pragma unroll
    for (int k = 0; k < 4; k++) {
        int r = tr + k * 8;
        vtb[((size_t)b * D_ + d0 + r) * S_ + s0 + tc] = tile[tc][r];
    }
}

__global__ __launch_bounds__(256) void transpose_v_f16(
    const bf16* __restrict__ vb, f16* __restrict__ vtb)
{
    __shared__ bf16 tile[32][33];
    const int b = blockIdx.z;
    const int s0 = blockIdx.x * 32, d0 = blockIdx.y * 32;
    const int tr = threadIdx.x >> 5;
    const int tc = threadIdx.x & 31;
#pragma unroll
    for (int k = 0; k < 4; k++) {
        int r = tr + k * 8;
        tile[r][tc] = vb[((size_t)b * S_ + s0 + r) * D_ + d0 + tc];
    }
    __syncthreads();
#pragma unroll
    for (int k = 0; k < 4; k++) {
        int r = tr + k * 8;
        vtb[((size_t)b * D_ + d0 + r) * S_ + s0 + tc] = (f16)(float)tile[tc][r];
    }
}

// ---------------------------------------------------------------------------
// softmax over one 4096-row of f16 scores, in place (normalized f16 out)
// ---------------------------------------------------------------------------
__global__ __launch_bounds__(256) void softmax_inplace_f16(f16* __restrict__ Sc)
{
    f16* row = Sc + (size_t)blockIdx.x * S_;
    const int tid = threadIdx.x, wave = tid >> 6, lane = tid & 63;
    __shared__ float redm[4], redl[4];

    f16x8 a = *(const f16x8*)(row + tid * 16);
    f16x8 b = *(const f16x8*)(row + tid * 16 + 8);
    float v[16];
#pragma unroll
    for (int j = 0; j < 8; j++) { v[j] = (float)a[j]; v[8 + j] = (float)b[j]; }

    float m = -1e30f;
#pragma unroll
    for (int j = 0; j < 16; j++) m = fmaxf(m, v[j]);
#pragma unroll
    for (int off = 32; off; off >>= 1) m = fmaxf(m, __shfl_xor(m, off));
    if (lane == 0) redm[wave] = m;
    __syncthreads();
    m = fmaxf(fmaxf(redm[0], redm[1]), fmaxf(redm[2], redm[3]));

    float s = 0.0f;
#pragma unroll
    for (int j = 0; j < 16; j++) { v[j] = __expf(v[j] - m); s += v[j]; }
#pragma unroll
    for (int off = 32; off; off >>= 1) s += __shfl_xor(s, off);
    if (lane == 0) redl[wave] = s;
    __syncthreads();
    s = redl[0] + redl[1] + redl[2] + redl[3];
    float inv = 1.0f / s;

#pragma unroll
    for (int j = 0; j < 8; j++) { a[j] = (f16)(v[j] * inv); b[j] = (f16)(v[8 + j] * inv); }
    *(f16x8*)(row + tid * 16) = a;
    *(f16x8*)(row + tid * 16 + 8) = b;
}

// ---------------------------------------------------------------------------
// softmax over one fp32 score row -> normalized fp16 (per-batch fallback)
// ---------------------------------------------------------------------------
__global__ __launch_bounds__(256) void softmax_row(
    const float* __restrict__ Sc, f16* __restrict__ P)
{
    const int q = blockIdx.x;
    const float* row = Sc + (size_t)q * S_;
    f16* prow = P + (size_t)q * S_;
    const int tid = threadIdx.x, wave = tid >> 6, lane = tid & 63;

    float4 v[4];
#pragma unroll
    for (int i = 0; i < 4; i++) v[i] = *(const float4*)(row + tid * 16 + i * 4);

    float m = -1e30f;
#pragma unroll
    for (int i = 0; i < 4; i++)
        m = fmaxf(m, fmaxf(fmaxf(v[i].x, v[i].y), fmaxf(v[i].z, v[i].w)));
#pragma unroll
    for (int off = 32; off; off >>= 1) m = fmaxf(m, __shfl_xor(m, off));
    __shared__ float redm[4], redl[4];
    if (lane == 0) redm[wave] = m;
    __syncthreads();
    m = fmaxf(fmaxf(redm[0], redm[1]), fmaxf(redm[2], redm[3]));

    float p[16];
    float s = 0.0f;
#pragma unroll
    for (int i = 0; i < 4; i++) {
        p[i * 4 + 0] = __expf(v[i].x - m);
        p[i * 4 + 1] = __expf(v[i].y - m);
        p[i * 4 + 2] = __expf(v[i].z - m);
        p[i * 4 + 3] = __expf(v[i].w - m);
        s += p[i * 4] + p[i * 4 + 1] + p[i * 4 + 2] + p[i * 4 + 3];
    }
#pragma unroll
    for (int off = 32; off; off >>= 1) s += __shfl_xor(s, off);
    if (lane == 0) redl[wave] = s;
    __syncthreads();
    s = redl[0] + redl[1] + redl[2] + redl[3];
    float inv = 1.0f / s;

    f16x8 o0, o1;
#pragma unroll
    for (int j = 0; j < 8; j++) {
        o0[j] = (f16)(p[j] * inv);
        o1[j] = (f16)(p[8 + j] * inv);
    }
    *(f16x8*)(prow + tid * 16) = o0;
    *(f16x8*)(prow + tid * 16 + 8) = o1;
}

// ---------------------------------------------------------------------------
// legacy fp32-input proj (flash fallback only)
// ---------------------------------------------------------------------------
#define SSTR 40
__global__ __launch_bounds__(256) void proj_gemm(
    const float* __restrict__ A, const float* __restrict__ W,
    const float* __restrict__ bias1, const float* __restrict__ bias2,
    bf16* __restrict__ C, float scale)
{
    __shared__ bf16 sA[64 * SSTR];
    __shared__ bf16 sB[64 * SSTR];
    const int tid = threadIdx.x;
    const int wave = tid >> 6, lane = tid & 63, quad = lane >> 4, l16 = lane & 15;
    const int m0 = blockIdx.x * 64, n0 = blockIdx.y * 64;
    const int wr = (wave >> 1) * 32, wc = (wave & 1) * 32;
    const int lr = tid >> 2;
    const int lc = (tid & 3) * 8;

    floatx4 acc[2][2];
#pragma unroll
    for (int i = 0; i < 2; i++)
#pragma unroll
        for (int j = 0; j < 2; j++) acc[i][j] = (floatx4)0.0f;

    for (int k0 = 0; k0 < 1024; k0 += 32) {
        const float* ga = A + (size_t)(m0 + lr) * 1024 + k0 + lc;
        const float* gw = W + (size_t)(n0 + lr) * 1024 + k0 + lc;
        float4 a0 = *(const float4*)ga;
        float4 a1 = *(const float4*)(ga + 4);
        float4 w0 = *(const float4*)gw;
        float4 w1 = *(const float4*)(gw + 4);
        *(bf16x8*)&sA[lr * SSTR + lc] = cvt8(a0, a1);
        *(bf16x8*)&sB[lr * SSTR + lc] = cvt8(w0, w1);
        __syncthreads();
        bf16x8 af[2], bfv[2];
        af[0]  = *(bf16x8*)&sA[(wr + l16) * SSTR + quad * 8];
        af[1]  = *(bf16x8*)&sA[(wr + 16 + l16) * SSTR + quad * 8];
        bfv[0] = *(bf16x8*)&sB[(wc + l16) * SSTR + quad * 8];
        bfv[1] = *(bf16x8*)&sB[(wc + 16 + l16) * SSTR + quad * 8];
#pragma unroll
        for (int mf = 0; mf < 2; mf++)
#pragma unroll
            for (int nf = 0; nf < 2; nf++)
                acc[mf][nf] = mfma16(af[mf], bfv[nf], acc[mf][nf]);
        __syncthreads();
    }
#pragma unroll
    for (int mf = 0; mf < 2; mf++)
#pragma unroll
        for (int nf = 0; nf < 2; nf++) {
            int col = n0 + wc + nf * 16 + l16;
            float bsum = bias1[col] + (bias2 ? bias2[col] : 0.0f);
#pragma unroll
            for (int r = 0; r < 4; r++) {
                int row = m0 + wr + mf * 16 + quad * 4 + r;
                C[(size_t)row * 1024 + col] = (bf16)((acc[mf][nf][r] + bsum) * scale);
            }
        }
}

// ---------------------------------------------------------------------------
// flash fallback (only if ws < 192MB)
// ---------------------------------------------------------------------------
#define BR 32
#define TK 64
#define DC 256
__global__ __launch_bounds__(256, 2) void flash_attn(
    const bf16* __restrict__ qb, const bf16* __restrict__ vb,
    const bf16* __restrict__ vtb, float* __restrict__ out)
{
    __shared__ float sPart[4][32][65];
    __shared__ bf16 sP[32][72];
    __shared__ float sM[32], sL[32], sAlpha[32];

    const int tid = threadIdx.x;
    const int wave = tid >> 6, lane = tid & 63, quad = lane >> 4, l16 = lane & 15;
    const int b = blockIdx.y, q0 = blockIdx.x * BR;

    bf16x8 qf[2][8];
#pragma unroll
    for (int mf = 0; mf < 2; mf++)
#pragma unroll
        for (int ks = 0; ks < 8; ks++) {
            int row = q0 + mf * 16 + l16;
            int col = wave * DC + ks * 32 + quad * 8;
            qf[mf][ks] = *(const bf16x8*)(qb + ((size_t)b * S_ + row) * D_ + col);
        }

    floatx4 o[2][16];
#pragma unroll
    for (int mf = 0; mf < 2; mf++)
#pragma unroll
        for (int nf = 0; nf < 16; nf++) o[mf][nf] = (floatx4)0.0f;

    if (tid < 32) { sM[tid] = -1e30f; sL[tid] = 0.0f; }
    __syncthreads();

    for (int kt = 0; kt < S_ / TK; kt++) {
        const int k0 = kt * TK;
        floatx4 sp[2][4];
#pragma unroll
        for (int mf = 0; mf < 2; mf++)
#pragma unroll
            for (int nf = 0; nf < 4; nf++) sp[mf][nf] = (floatx4)0.0f;
#pragma unroll
        for (int ks = 0; ks < 8; ks++) {
            int col = wave * DC + ks * 32 + quad * 8;
#pragma unroll
            for (int nf = 0; nf < 4; nf++) {
                int key = k0 + nf * 16 + l16;
                bf16x8 vf = *(const bf16x8*)(vb + ((size_t)b * S_ + key) * D_ + col);
                sp[0][nf] = mfma16(qf[0][ks], vf, sp[0][nf]);
                sp[1][nf] = mfma16(qf[1][ks], vf, sp[1][nf]);
            }
        }
#pragma unroll
        for (int mf = 0; mf < 2; mf++)
#pragma unroll
            for (int nf = 0; nf < 4; nf++)
#pragma unroll
                for (int r = 0; r < 4; r++)
                    sPart[wave][mf * 16 + quad * 4 + r][nf * 16 + l16] = sp[mf][nf][r];
        __syncthreads();

        {
            const int rr = tid >> 3, c0 = (tid & 7) * 8;
            float v[8];
            float mx = -1e30f;
#pragma unroll
            for (int j = 0; j < 8; j++) {
                v[j] = sPart[0][rr][c0 + j] + sPart[1][rr][c0 + j] +
                       sPart[2][rr][c0 + j] + sPart[3][rr][c0 + j];
                mx = fmaxf(mx, v[j]);
            }
            mx = fmaxf(mx, __shfl_xor(mx, 1));
            mx = fmaxf(mx, __shfl_xor(mx, 2));
            mx = fmaxf(mx, __shfl_xor(mx, 4));
            float m_old = sM[rr];
            float m_new = fmaxf(m_old, mx);
            float rsum = 0.0f;
#pragma unroll
            for (int j = 0; j < 8; j++) {
                float p = __expf(v[j] - m_new);
                sP[rr][c0 + j] = (bf16)p;
                rsum += p;
            }
            rsum += __shfl_xor(rsum, 1);
            rsum += __shfl_xor(rsum, 2);
            rsum += __shfl_xor(rsum, 4);
            if ((tid & 7) == 0) {
                float alpha = __expf(m_old - m_new);
                sAlpha[rr] = alpha;
                sM[rr] = m_new;
                sL[rr] = sL[rr] * alpha + rsum;
            }
        }
        __syncthreads();

        float al[2][4];
#pragma unroll
        for (int mf = 0; mf < 2; mf++)
#pragma unroll
            for (int r = 0; r < 4; r++) al[mf][r] = sAlpha[mf * 16 + quad * 4 + r];
#pragma unroll
        for (int mf = 0; mf < 2; mf++)
#pragma unroll
            for (int nf = 0; nf < 16; nf++)
#pragma unroll
                for (int r = 0; r < 4; r++) o[mf][nf][r] *= al[mf][r];

#pragma unroll
        for (int ks2 = 0; ks2 < 2; ks2++) {
            bf16x8 pA[2];
            pA[0] = *(bf16x8*)&sP[l16][ks2 * 32 + quad * 8];
            pA[1] = *(bf16x8*)&sP[16 + l16][ks2 * 32 + quad * 8];
            int key = k0 + ks2 * 32 + quad * 8;
#pragma unroll
            for (int nf = 0; nf < 16; nf++) {
                int d = wave * DC + nf * 16 + l16;
                bf16x8 vtf = *(const bf16x8*)(vtb + ((size_t)b * D_ + d) * S_ + key);
                o[0][nf] = mfma16(pA[0], vtf, o[0][nf]);
                o[1][nf] = mfma16(pA[1], vtf, o[1][nf]);
            }
        }
        __syncthreads();
    }

#pragma unroll
    for (int mf = 0; mf < 2; mf++) {
        float inv[4];
#pragma unroll
        for (int r = 0; r < 4; r++) inv[r] = 1.0f / sL[mf * 16 + quad * 4 + r];
#pragma unroll
        for (int nf = 0; nf < 16; nf++) {
            int d = wave * DC + nf * 16 + l16;
#pragma unroll
            for (int r = 0; r < 4; r++) {
                int row = q0 + mf * 16 + quad * 4 + r;
                out[((size_t)b * S_ + row) * D_ + d] = o[mf][nf][r] * inv[r];
            }
        }
    }
}

// ---------------------------------------------------------------------------
extern "C" void kernel_launch(void* const* d_in, const int* in_sizes, int n_in,
                              void* d_out, int out_size, void* d_ws, size_t ws_size,
                              hipStream_t stream) {
    const float* query = (const float*)d_in[0];
    const float* value = (const float*)d_in[1];
    const float* Wq    = (const float*)d_in[2];
    const float* bq    = (const float*)d_in[3];
    const float* qk_b  = (const float*)d_in[4];
    const float* Wv    = (const float*)d_in[5];
    const float* bv    = (const float*)d_in[6];
    float* out = (float*)d_out;

    const size_t SD = (size_t)S_ * D_;   // 4.19M elems
    const size_t SS = (size_t)S_ * S_;   // 16.8M elems
    const size_t MB = 1024 * 1024;

    char* w = (char*)d_ws;
    bf16* qb = (bf16*)w;                  // 32 MB (scale+bias folded)
    bf16* vb = (bf16*)(w + 32 * MB);      // 32 MB

    if (ws_size >= 224 * MB) {
        // ---- full batched path (256^2 pipelined GEMMs, 32x32 MFMA) ----
        f16* vtb = (f16*)(w + 64 * MB);   // 32 MB [b][d][s]
        f16* Sc  = (f16*)(w + 96 * MB);   // 128 MB [b][q][k]; softmax in place
        bf16* qc  = (bf16*)(w + 96 * MB);   // 32 MB (aliases Sc until written)
        bf16* vc  = (bf16*)(w + 128 * MB);  // 32 MB
        bf16* wqc = (bf16*)(w + 160 * MB);  // 2 MB
        bf16* wvc = (bf16*)(w + 163 * MB);  // 2 MB

        cast_f32_bf16<<<(B_ * SD) / 2048, 256, 0, stream>>>(query, qc);
        cast_f32_bf16<<<(B_ * SD) / 2048, 256, 0, stream>>>(value, vc);
        cast_f32_bf16<<<((size_t)D_ * D_) / 2048, 256, 0, stream>>>(Wq, wqc);
        cast_f32_bf16<<<((size_t)D_ * D_) / 2048, 256, 0, stream>>>(Wv, wvc);

        gemm256<bf16, bf16, true><<<dim3(256, 1, 1), 512, 0, stream>>>(
            qc, wqc, qb, D_, D_, 0, 0, 0, bq, qk_b, 0.125f, 4);
        gemm256<bf16, bf16, true><<<dim3(256, 1, 1), 512, 0, stream>>>(
            vc, wvc, vb, D_, D_, 0, 0, 0, bv, nullptr, 1.0f, 4);

        transpose_v_f16<<<dim3(S_ / 32, D_ / 32, B_), 256, 0, stream>>>(vb, vtb);

        gemm256<bf16, f16, false><<<dim3(256, 1, B_), 512, 0, stream>>>(
            qb, vb, Sc, D_, S_, SD, SD, SS, nullptr, nullptr, 1.0f, 16);

        softmax_inplace_f16<<<B_ * S_, 256, 0, stream>>>(Sc);

        gemm256<f16, float, false><<<dim3(64, 1, B_), 512, 0, stream>>>(
            Sc, vtb, out, S_, D_, SS, (size_t)D_ * S_, SD, nullptr, nullptr, 1.0f, 4);
    } else if (ws_size >= 192 * MB) {
        // ---- per-batch fallback (fp32 scores) ----
        f16*   vtb = (f16*)(w + 64 * MB);
        float* Sc  = (float*)(w + 96 * MB);
        f16*   Pn  = (f16*)(w + 160 * MB);
        bf16*  qc  = (bf16*)(w + 96 * MB);
        bf16*  vc  = (bf16*)(w + 128 * MB);
        bf16*  wqc = (bf16*)(w + 160 * MB);
        bf16*  wvc = (bf16*)(w + 163 * MB);

        cast_f32_bf16<<<(B_ * SD) / 2048, 256, 0, stream>>>(query, qc);
        cast_f32_bf16<<<(B_ * SD) / 2048, 256, 0, stream>>>(value, vc);
        cast_f32_bf16<<<((size_t)D_ * D_) / 2048, 256, 0, stream>>>(Wq, wqc);
        cast_f32_bf16<<<((size_t)D_ * D_) / 2048, 256, 0, stream>>>(Wv, wvc);

        gemm128<bf16, bf16, true><<<dim3(128, 8, 1), 256, 0, stream>>>(
            qc, wqc, qb, D_, D_, 0, 0, 0, bq, qk_b, 0.125f);
        gemm128<bf16, bf16, true><<<dim3(128, 8, 1), 256, 0, stream>>>(
            vc, wvc, vb, D_, D_, 0, 0, 0, bv, nullptr, 1.0f);

        transpose_v_f16<<<dim3(S_ / 32, D_ / 32, B_), 256, 0, stream>>>(vb, vtb);

        for (int b = 0; b < B_; b++) {
            gemm128<bf16, float, false><<<dim3(32, 32, 1), 256, 0, stream>>>(
                qb + b * SD, vb + b * SD, Sc, D_, S_, 0, 0, 0, nullptr, nullptr, 1.0f);
            softmax_row<<<S_, 256, 0, stream>>>(Sc, Pn);
            gemm128<f16, float, false><<<dim3(32, 8, 1), 256, 0, stream>>>(
                Pn, vtb + (size_t)b * D_ * S_, out + b * SD, S_, D_,
                0, 0, 0, nullptr, nullptr, 1.0f);
        }
    } else {
        // ---- flash fallback (96 MB) ----
        bf16* vtb = (bf16*)(w + 64 * MB);
        dim3 pg(16384 / 64, 1024 / 64);
        proj_gemm<<<pg, 256, 0, stream>>>(query, Wq, bq, qk_b, qb, 0.125f);
        proj_gemm<<<pg, 256, 0, stream>>>(value, Wv, bv, nullptr, vb, 1.0f);
        transpose_v<<<dim3(S_ / 32, D_ / 32, B_), 256, 0, stream>>>(vb, vtb);
        flash_attn<<<dim3(S_ / BR, B_), 256, 0, stream>>>(qb, vb, vtb, out);
    }
}

// Round 9
// 577.528 us; speedup vs baseline: 1.1109x; 1.1109x over previous
//
#include <hip/hip_runtime.h>

#define B_ 4
#define S_ 4096
#define D_ 1024

typedef __bf16 bf16;
typedef _Float16 f16;
typedef __attribute__((ext_vector_type(8))) __bf16 bf16x8;
typedef __attribute__((ext_vector_type(8))) _Float16 f16x8;
typedef __attribute__((ext_vector_type(4))) float floatx4;
typedef __attribute__((ext_vector_type(16))) float floatx16;

__device__ inline floatx4 mfma16(bf16x8 a, bf16x8 b, floatx4 c) {
    return __builtin_amdgcn_mfma_f32_16x16x32_bf16(a, b, c, 0, 0, 0);
}
__device__ inline floatx4 mfma_any(bf16x8 a, bf16x8 b, floatx4 c) {
    return __builtin_amdgcn_mfma_f32_16x16x32_bf16(a, b, c, 0, 0, 0);
}
__device__ inline floatx4 mfma_any(f16x8 a, f16x8 b, floatx4 c) {
    return __builtin_amdgcn_mfma_f32_16x16x32_f16(a, b, c, 0, 0, 0);
}
// 32x32x16 variants: A/B = 8 elems/lane, C/D = 16 f32/lane.
__device__ inline floatx16 mfma_any(bf16x8 a, bf16x8 b, floatx16 c) {
    return __builtin_amdgcn_mfma_f32_32x32x16_bf16(a, b, c, 0, 0, 0);
}
__device__ inline floatx16 mfma_any(f16x8 a, f16x8 b, floatx16 c) {
    return __builtin_amdgcn_mfma_f32_32x32x16_f16(a, b, c, 0, 0, 0);
}

template <typename T> struct vec8_of;
template <> struct vec8_of<bf16> { using type = bf16x8; };
template <> struct vec8_of<f16>  { using type = f16x8; };

__device__ inline bf16x8 cvt8(float4 a, float4 b) {
    bf16x8 h;
    h[0] = (bf16)a.x; h[1] = (bf16)a.y; h[2] = (bf16)a.z; h[3] = (bf16)a.w;
    h[4] = (bf16)b.x; h[5] = (bf16)b.y; h[6] = (bf16)b.z; h[7] = (bf16)b.w;
    return h;
}

// ---------------------------------------------------------------------------
// elementwise fp32 -> bf16 cast (n multiple of 2048)
// ---------------------------------------------------------------------------
__global__ __launch_bounds__(256) void cast_f32_bf16(
    const float* __restrict__ in, bf16* __restrict__ out)
{
    size_t i = ((size_t)blockIdx.x * 256 + threadIdx.x) * 8;
    float4 a = *(const float4*)(in + i);
    float4 b = *(const float4*)(in + i + 4);
    *(bf16x8*)(out + i) = cvt8(a, b);
}

// ---------------------------------------------------------------------------
// gemm256 v8: 32x32x16 MFMA with a BLOCK-ROTATED LDS layout that is BOTH
// stage-coalesced AND read-conflict-free (round-7 paid LDS conflicts, round-8
// paid HBM scatter; this satisfies both constraints simultaneously):
//  - half-tile = 32 blocks of 4 rows (512B, bank-cycle-aligned). Within
//    block jb, chunk c = (row&3)*8 + (e8 ^ (jb&7))  [e8 = 16B piece of row].
//  - STAGE (LDS-linear, per-lane global src): idx -> jb=idx>>5, c=idx&31,
//    row=jb*4+(c>>3), e8=(c&7)^(jb&7). Per wave: 2 blocks = 8 COMPLETE
//    128B rows (coalesced; within-row order permuted only).
//  - READ rd(i,ks): lane offset i*2048 + h*256 + (l32&3)*64 + ((ks2)^h)*8
//    elems (h=l32>>2, ks2=ks*2+kg). Decodes to row i*32+l32, elems
//    ks*16+kg*8 (the numerically-verified fragment). Slot (mod 128B) =
//    (ks2^h): h spans 0..7 x4 lanes, kg flips bit0 -> 8 lanes/slot =
//    the same uniformity class as the round-6 measured-0-conflict pattern.
// Schedule identical to rounds 6-8: 4 phases/K-tile, stage A(t+1)h1@P1,
// B(t+2)h0@P3, B(t+2)h1+A(t+2)h0@P4, single vmcnt(6)/tile (3 half-tiles in
// flight), compile-time buffer parity, patch-major+XCD tile order, setprio.
// ---------------------------------------------------------------------------
template <typename TI, typename TO, bool HAS_BIAS>
__global__ __launch_bounds__(512, 2) void gemm256(
    const TI* __restrict__ A, const TI* __restrict__ B, TO* __restrict__ C,
    int K, int ldc, size_t strideA, size_t strideB, size_t strideC,
    const float* __restrict__ bias1, const float* __restrict__ bias2,
    float scale, int tiles_n)
{
    using v8 = typename vec8_of<TI>::type;
    __shared__ __align__(16) TI sA[2][2][8192];
    __shared__ __align__(16) TI sB[2][2][8192];

    A += (size_t)blockIdx.z * strideA;
    B += (size_t)blockIdx.z * strideB;
    C += (size_t)blockIdx.z * strideC;

    const int tid = threadIdx.x;
    const int wave = tid >> 6, lane = tid & 63;
    const int l32 = lane & 31, kg = lane >> 5;
    const int wm = wave >> 2, wn = wave & 3;

    // XCD-bijective chunking + 4x4 patch-major tile order
    const int gx = gridDim.x;
    const int cpx = gx >> 3;
    const int lid = (blockIdx.x & 7) * cpx + (blockIdx.x >> 3);
    const int p = lid >> 4, w = lid & 15;
    const int pr = tiles_n >> 2;
    const int Pm = p / pr, Pn = p - Pm * pr;
    const int tm = Pm * 4 + (w >> 2), tn = Pn * 4 + (w & 3);
    const int m0 = tm * 256, n0 = tn * 256;

    const TI* Abase = A + (size_t)m0 * K;
    const TI* Bbase = B + (size_t)n0 * K;

    // staging source map: chunk idx (16B) -> block-rotated position.
    size_t goff[2];
#pragma unroll
    for (int j = 0; j < 2; j++) {
        int idx = j * 512 + tid;
        int jb = idx >> 5, c = idx & 31;
        int r = jb * 4 + (c >> 3);
        int e8 = (c & 7) ^ (jb & 7);
        goff[j] = (size_t)r * K + e8 * 8;
    }
    const int NT = K >> 6;
    const size_t halfA = (size_t)128 * K;

    auto stageA = [&](int t, int half, int bufsel) {
#pragma unroll
        for (int j = 0; j < 2; j++) {
            int idx = j * 512 + tid;
            __builtin_amdgcn_global_load_lds(
                (const __attribute__((address_space(1))) void*)(
                    Abase + (size_t)t * 64 + (half ? halfA : 0) + goff[j]),
                (__attribute__((address_space(3))) void*)(sA[bufsel][half] + idx * 8),
                16, 0, 0);
        }
    };
    auto stageB = [&](int t, int half, int bufsel) {
#pragma unroll
        for (int j = 0; j < 2; j++) {
            int idx = j * 512 + tid;
            __builtin_amdgcn_global_load_lds(
                (const __attribute__((address_space(1))) void*)(
                    Bbase + (size_t)t * 64 + (half ? halfA : 0) + goff[j]),
                (__attribute__((address_space(3))) void*)(sB[bufsel][half] + idx * 8),
                16, 0, 0);
        }
    };
    // fragment reads: block-rotated, conflict-free. A-half = wm;
    // B-half = wn>>1; B window within half = wn&1.
    const int h_ = l32 >> 2, q4_ = (l32 & 3) * 64 + h_ * 256;
    auto rdA = [&](int buf, int i, int ks) -> v8 {
        int off = i * 2048 + q4_ + ((((ks << 1) | kg) ^ h_) << 3);
        return *(const v8*)(sA[buf][wm] + off);
    };
    auto rdB = [&](int buf, int jf, int ks) -> v8 {
        int ii = (wn & 1) * 2 + jf;
        int off = ii * 2048 + q4_ + ((((ks << 1) | kg) ^ h_) << 3);
        return *(const v8*)(sB[buf][wn >> 1] + off);
    };

    floatx16 acc[4][2];
#pragma unroll
    for (int i = 0; i < 4; i++)
#pragma unroll
        for (int j = 0; j < 2; j++) acc[i][j] = (floatx16)0.0f;

    // prologue: tile0 (4 half-tiles) + B(1)h0,h1 + A(1)h0; vmcnt(6).
    {
        int t1 = (1 < NT) ? 1 : 0;
        stageA(0, 0, 0); stageA(0, 1, 0);
        stageB(0, 0, 0); stageB(0, 1, 0);
        stageB(t1, 0, 1); stageB(t1, 1, 1);
        stageA(t1, 0, 1);
        asm volatile("s_waitcnt vmcnt(6)" ::: "memory");
        __builtin_amdgcn_s_barrier();
    }

    v8 a[8], b0[4], b1[4];
    for (int u = 0; u < NT; u += 2) {
#pragma unroll
        for (int half_it = 0; half_it < 2; half_it++) {
            const int t = u + half_it;
            const int buf = half_it;                        // compile-time
            const int tA = (t + 1 < NT) ? t + 1 : NT - 1;
            const int tB = (t + 2 < NT) ? t + 2 : NT - 1;

            // ---- P1: Q11 m01 x n0 ; reads a01(8) + b0(4) ; stage A(t+1)h1 ----
#pragma unroll
            for (int i = 0; i < 2; i++)
#pragma unroll
                for (int ks = 0; ks < 4; ks++) a[i * 4 + ks] = rdA(buf, i, ks);
#pragma unroll
            for (int ks = 0; ks < 4; ks++) b0[ks] = rdB(buf, 0, ks);
            stageA(tA, 1, buf ^ 1);
            __builtin_amdgcn_s_barrier();
            __builtin_amdgcn_s_setprio(1);
#pragma unroll
            for (int i = 0; i < 2; i++)
#pragma unroll
                for (int ks = 0; ks < 4; ks++)
                    acc[i][0] = mfma_any(a[i * 4 + ks], b0[ks], acc[i][0]);
            __builtin_amdgcn_s_setprio(0);
            __builtin_amdgcn_s_barrier();

            // ---- P2: Q12 m01 x n1 ; reads b1(4) ----
#pragma unroll
            for (int ks = 0; ks < 4; ks++) b1[ks] = rdB(buf, 1, ks);
            __builtin_amdgcn_s_barrier();
            __builtin_amdgcn_s_setprio(1);
#pragma unroll
            for (int i = 0; i < 2; i++)
#pragma unroll
                for (int ks = 0; ks < 4; ks++)
                    acc[i][1] = mfma_any(a[i * 4 + ks], b1[ks], acc[i][1]);
            __builtin_amdgcn_s_setprio(0);
            __builtin_amdgcn_s_barrier();

            // ---- P3: Q22 m23 x n1 ; reads a23(8) ; stage B(t+2)h0 ----
#pragma unroll
            for (int i = 0; i < 2; i++)
#pragma unroll
                for (int ks = 0; ks < 4; ks++) a[i * 4 + ks] = rdA(buf, 2 + i, ks);
            stageB(tB, 0, buf);
            __builtin_amdgcn_s_barrier();
            __builtin_amdgcn_s_setprio(1);
#pragma unroll
            for (int i = 0; i < 2; i++)
#pragma unroll
                for (int ks = 0; ks < 4; ks++)
                    acc[2 + i][1] = mfma_any(a[i * 4 + ks], b1[ks], acc[2 + i][1]);
            __builtin_amdgcn_s_setprio(0);
            __builtin_amdgcn_s_barrier();

            // ---- P4: Q21 m23 x n0 ; stage B(t+2)h1 + A(t+2)h0 ; vmcnt(6) ----
            stageB(tB, 1, buf);
            stageA(tB, 0, buf);
            asm volatile("s_waitcnt vmcnt(6)" ::: "memory");
            __builtin_amdgcn_s_barrier();
            __builtin_amdgcn_s_setprio(1);
#pragma unroll
            for (int i = 0; i < 2; i++)
#pragma unroll
                for (int ks = 0; ks < 4; ks++)
                    acc[2 + i][0] = mfma_any(a[i * 4 + ks], b0[ks], acc[2 + i][0]);
            __builtin_amdgcn_s_setprio(0);
            __builtin_amdgcn_s_barrier();
        }
    }

    // epilogue: col=lane&31, row=(reg&3)+8*(reg>>2)+4*(lane>>5)
#pragma unroll
    for (int mf = 0; mf < 4; mf++)
#pragma unroll
        for (int nf = 0; nf < 2; nf++) {
            int col = n0 + wn * 64 + nf * 32 + l32;
            float badd = 0.0f;
            if (HAS_BIAS) {
                badd = bias1[col];
                if (bias2) badd += bias2[col];
            }
#pragma unroll
            for (int r = 0; r < 16; r++) {
                int row = m0 + wm * 128 + mf * 32 + (r & 3) + 8 * (r >> 2) + 4 * kg;
                float v = acc[mf][nf][r];
                if (HAS_BIAS) v = (v + badd) * scale;
                C[(size_t)row * ldc + col] = (TO)v;
            }
        }
}

// ---------------------------------------------------------------------------
// m97-style GEMM (kept for fallback paths)
// ---------------------------------------------------------------------------
template <typename TI, typename TO, bool HAS_BIAS>
__global__ __launch_bounds__(256) void gemm128(
    const TI* __restrict__ A, const TI* __restrict__ B, TO* __restrict__ C,
    int K, int ldc, size_t strideA, size_t strideB, size_t strideC,
    const float* __restrict__ bias1, const float* __restrict__ bias2, float scale)
{
    using v8 = typename vec8_of<TI>::type;
    __shared__ TI sA[2 * 128 * 32];
    __shared__ TI sB[2 * 128 * 32];
    A += (size_t)blockIdx.z * strideA;
    B += (size_t)blockIdx.z * strideB;
    C += (size_t)blockIdx.z * strideC;

    const int tid = threadIdx.x;
    const int wave = tid >> 6, lane = tid & 63, quad = lane >> 4, l16 = lane & 15;
    const int m0 = blockIdx.x * 128, n0 = blockIdx.y * 128;
    const int wr = (wave >> 1) * 64, wc = (wave & 1) * 64;

    floatx4 acc[4][4];
#pragma unroll
    for (int i = 0; i < 4; i++)
#pragma unroll
        for (int j = 0; j < 4; j++) acc[i][j] = (floatx4)0.0f;

    for (int k0 = 0; k0 < K; k0 += 64) {
#pragma unroll
        for (int s = 0; s < 2; s++) {
#pragma unroll
            for (int j = 0; j < 2; j++) {
                int idx = j * 256 + tid;
                int r = idx >> 2, c = (idx & 3) * 8;
                __builtin_amdgcn_global_load_lds(
                    (const __attribute__((address_space(1))) void*)(A + (size_t)(m0 + r) * K + k0 + s * 32 + c),
                    (__attribute__((address_space(3))) void*)(sA + s * 4096 + idx * 8), 16, 0, 0);
                __builtin_amdgcn_global_load_lds(
                    (const __attribute__((address_space(1))) void*)(B + (size_t)(n0 + r) * K + k0 + s * 32 + c),
                    (__attribute__((address_space(3))) void*)(sB + s * 4096 + idx * 8), 16, 0, 0);
            }
        }
        __syncthreads();
#pragma unroll
        for (int s = 0; s < 2; s++) {
            v8 af[4], bfv[4];
#pragma unroll
            for (int i = 0; i < 4; i++) {
                af[i]  = *(const v8*)&sA[s * 4096 + (wr + i * 16 + l16) * 32 + quad * 8];
                bfv[i] = *(const v8*)&sB[s * 4096 + (wc + i * 16 + l16) * 32 + quad * 8];
            }
#pragma unroll
            for (int mf = 0; mf < 4; mf++)
#pragma unroll
                for (int nf = 0; nf < 4; nf++)
                    acc[mf][nf] = mfma_any(af[mf], bfv[nf], acc[mf][nf]);
        }
        __syncthreads();
    }

#pragma unroll
    for (int mf = 0; mf < 4; mf++)
#pragma unroll
        for (int nf = 0; nf < 4; nf++) {
            int col = n0 + wc + nf * 16 + l16;
            float badd = 0.0f;
            if (HAS_BIAS) {
                badd = bias1[col];
                if (bias2) badd += bias2[col];
            }
#pragma unroll
            for (int r = 0; r < 4; r++) {
                int row = m0 + wr + mf * 16 + quad * 4 + r;
                float v = acc[mf][nf][r];
                if (HAS_BIAS) v = (v + badd) * scale;
                C[(size_t)row * ldc + col] = (TO)v;
            }
        }
}

// ---------------------------------------------------------------------------
// transposes: vb [b][s][d] -> vtb [b][d][s]
// ---------------------------------------------------------------------------
__global__ __launch_bounds__(256) void transpose_v(
    const bf16* __restrict__ vb, bf16* __restrict__ vtb)
{
    __shared__ bf16 tile[32][33];
    const int b = blockIdx.z;
    const int s0 = blockIdx.x * 32, d0 = blockIdx.y * 32;
    const int tr = threadIdx.x >> 5;
    const int tc = threadIdx.x & 31;
#pragma unroll
    for (int k = 0; k < 4; k++) {
        int r = tr + k * 8;
        tile[r][tc] = vb[((size_t)b * S_ + s0 + r) * D_ + d0 + tc];
    }
    __syncthreads();
#pragma unroll
    for (int k = 0; k < 4; k++) {
        int r = tr + k * 8;
        vtb[((size_t)b * D_ + d0 + r) * S_ + s0 + tc] = tile[tc][r];
    }
}

__global__ __launch_bounds__(256) void transpose_v_f16(
    const bf16* __restrict__ vb, f16* __restrict__ vtb)
{
    __shared__ bf16 tile[32][33];
    const int b = blockIdx.z;
    const int s0 = blockIdx.x * 32, d0 = blockIdx.y * 32;
    const int tr = threadIdx.x >> 5;
    const int tc = threadIdx.x & 31;
#pragma unroll
    for (int k = 0; k < 4; k++) {
        int r = tr + k * 8;
        tile[r][tc] = vb[((size_t)b * S_ + s0 + r) * D_ + d0 + tc];
    }
    __syncthreads();
#pragma unroll
    for (int k = 0; k < 4; k++) {
        int r = tr + k * 8;
        vtb[((size_t)b * D_ + d0 + r) * S_ + s0 + tc] = (f16)(float)tile[tc][r];
    }
}

// ---------------------------------------------------------------------------
// softmax over one 4096-row of f16 scores, in place (normalized f16 out)
// ---------------------------------------------------------------------------
__global__ __launch_bounds__(256) void softmax_inplace_f16(f16* __restrict__ Sc)
{
    f16* row = Sc + (size_t)blockIdx.x * S_;
    const int tid = threadIdx.x, wave = tid >> 6, lane = tid & 63;
    __shared__ float redm[4], redl[4];

    f16x8 a = *(const f16x8*)(row + tid * 16);
    f16x8 b = *(const f16x8*)(row + tid * 16 + 8);
    float v[16];
#pragma unroll
    for (int j = 0; j < 8; j++) { v[j] = (float)a[j]; v[8 + j] = (float)b[j]; }

    float m = -1e30f;
#pragma unroll
    for (int j = 0; j < 16; j++) m = fmaxf(m, v[j]);
#pragma unroll
    for (int off = 32; off; off >>= 1) m = fmaxf(m, __shfl_xor(m, off));
    if (lane == 0) redm[wave] = m;
    __syncthreads();
    m = fmaxf(fmaxf(redm[0], redm[1]), fmaxf(redm[2], redm[3]));

    float s = 0.0f;
#pragma unroll
    for (int j = 0; j < 16; j++) { v[j] = __expf(v[j] - m); s += v[j]; }
#pragma unroll
    for (int off = 32; off; off >>= 1) s += __shfl_xor(s, off);
    if (lane == 0) redl[wave] = s;
    __syncthreads();
    s = redl[0] + redl[1] + redl[2] + redl[3];
    float inv = 1.0f / s;

#pragma unroll
    for (int j = 0; j < 8; j++) { a[j] = (f16)(v[j] * inv); b[j] = (f16)(v[8 + j] * inv); }
    *(f16x8*)(row + tid * 16) = a;
    *(f16x8*)(row + tid * 16 + 8) = b;
}

// ---------------------------------------------------------------------------
// softmax over one fp32 score row -> normalized fp16 (per-batch fallback)
// ---------------------------------------------------------------------------
__global__ __launch_bounds__(256) void softmax_row(
    const float* __restrict__ Sc, f16* __restrict__ P)
{
    const int q = blockIdx.x;
    const float* row = Sc + (size_t)q * S_;
    f16* prow = P + (size_t)q * S_;
    const int tid = threadIdx.x, wave = tid >> 6, lane = tid & 63;

    float4 v[4];
#pragma unroll
    for (int i = 0; i < 4; i++) v[i] = *(const float4*)(row + tid * 16 + i * 4);

    float m = -1e30f;
#pragma unroll
    for (int i = 0; i < 4; i++)
        m = fmaxf(m, fmaxf(fmaxf(v[i].x, v[i].y), fmaxf(v[i].z, v[i].w)));
#pragma unroll
    for (int off = 32; off; off >>= 1) m = fmaxf(m, __shfl_xor(m, off));
    __shared__ float redm[4], redl[4];
    if (lane == 0) redm[wave] = m;
    __syncthreads();
    m = fmaxf(fmaxf(redm[0], redm[1]), fmaxf(redm[2], redm[3]));

    float p[16];
    float s = 0.0f;
#pragma unroll
    for (int i = 0; i < 4; i++) {
        p[i * 4 + 0] = __expf(v[i].x - m);
        p[i * 4 + 1] = __expf(v[i].y - m);
        p[i * 4 + 2] = __expf(v[i].z - m);
        p[i * 4 + 3] = __expf(v[i].w - m);
        s += p[i * 4] + p[i * 4 + 1] + p[i * 4 + 2] + p[i * 4 + 3];
    }
#pragma unroll
    for (int off = 32; off; off >>= 1) s += __shfl_xor(s, off);
    if (lane == 0) redl[wave] = s;
    __syncthreads();
    s = redl[0] + redl[1] + redl[2] + redl[3];
    float inv = 1.0f / s;

    f16x8 o0, o1;
#pragma unroll
    for (int j = 0; j < 8; j++) {
        o0[j] = (f16)(p[j] * inv);
        o1[j] = (f16)(p[8 + j] * inv);
    }
    *(f16x8*)(prow + tid * 16) = o0;
    *(f16x8*)(prow + tid * 16 + 8) = o1;
}

// ---------------------------------------------------------------------------
// legacy fp32-input proj (flash fallback only)
// ---------------------------------------------------------------------------
#define SSTR 40
__global__ __launch_bounds__(256) void proj_gemm(
    const float* __restrict__ A, const float* __restrict__ W,
    const float* __restrict__ bias1, const float* __restrict__ bias2,
    bf16* __restrict__ C, float scale)
{
    __shared__ bf16 sA[64 * SSTR];
    __shared__ bf16 sB[64 * SSTR];
    const int tid = threadIdx.x;
    const int wave = tid >> 6, lane = tid & 63, quad = lane >> 4, l16 = lane & 15;
    const int m0 = blockIdx.x * 64, n0 = blockIdx.y * 64;
    const int wr = (wave >> 1) * 32, wc = (wave & 1) * 32;
    const int lr = tid >> 2;
    const int lc = (tid & 3) * 8;

    floatx4 acc[2][2];
#pragma unroll
    for (int i = 0; i < 2; i++)
#pragma unroll
        for (int j = 0; j < 2; j++) acc[i][j] = (floatx4)0.0f;

    for (int k0 = 0; k0 < 1024; k0 += 32) {
        const float* ga = A + (size_t)(m0 + lr) * 1024 + k0 + lc;
        const float* gw = W + (size_t)(n0 + lr) * 1024 + k0 + lc;
        float4 a0 = *(const float4*)ga;
        float4 a1 = *(const float4*)(ga + 4);
        float4 w0 = *(const float4*)gw;
        float4 w1 = *(const float4*)(gw + 4);
        *(bf16x8*)&sA[lr * SSTR + lc] = cvt8(a0, a1);
        *(bf16x8*)&sB[lr * SSTR + lc] = cvt8(w0, w1);
        __syncthreads();
        bf16x8 af[2], bfv[2];
        af[0]  = *(bf16x8*)&sA[(wr + l16) * SSTR + quad * 8];
        af[1]  = *(bf16x8*)&sA[(wr + 16 + l16) * SSTR + quad * 8];
        bfv[0] = *(bf16x8*)&sB[(wc + l16) * SSTR + quad * 8];
        bfv[1] = *(bf16x8*)&sB[(wc + 16 + l16) * SSTR + quad * 8];
#pragma unroll
        for (int mf = 0; mf < 2; mf++)
#pragma unroll
            for (int nf = 0; nf < 2; nf++)
                acc[mf][nf] = mfma16(af[mf], bfv[nf], acc[mf][nf]);
        __syncthreads();
    }
#pragma unroll
    for (int mf = 0; mf < 2; mf++)
#pragma unroll
        for (int nf = 0; nf < 2; nf++) {
            int col = n0 + wc + nf * 16 + l16;
            float bsum = bias1[col] + (bias2 ? bias2[col] : 0.0f);
#pragma unroll
            for (int r = 0; r < 4; r++) {
                int row = m0 + wr + mf * 16 + quad * 4 + r;
                C[(size_t)row * 1024 + col] = (bf16)((acc[mf][nf][r] + bsum) * scale);
            }
        }
}

// ---------------------------------------------------------------------------
// flash fallback (only if ws < 192MB)
// ---------------------------------------------------------------------------
#define BR 32
#define TK 64
#define DC 256
__global__ __launch_bounds__(256, 2) void flash_attn(
    const bf16* __restrict__ qb, const bf16* __restrict__ vb,
    const bf16* __restrict__ vtb, float* __restrict__ out)
{
    __shared__ float sPart[4][32][65];
    __shared__ bf16 sP[32][72];
    __shared__ float sM[32], sL[32], sAlpha[32];

    const int tid = threadIdx.x;
    const int wave = tid >> 6, lane = tid & 63, quad = lane >> 4, l16 = lane & 15;
    const int b = blockIdx.y, q0 = blockIdx.x * BR;

    bf16x8 qf[2][8];
#pragma unroll
    for (int mf = 0; mf < 2; mf++)
#pragma unroll
        for (int ks = 0; ks < 8; ks++) {
            int row = q0 + mf * 16 + l16;
            int col = wave * DC + ks * 32 + quad * 8;
            qf[mf][ks] = *(const bf16x8*)(qb + ((size_t)b * S_ + row) * D_ + col);
        }

    floatx4 o[2][16];
#pragma unroll
    for (int mf = 0; mf < 2; mf++)
#pragma unroll
        for (int nf = 0; nf < 16; nf++) o[mf][nf] = (floatx4)0.0f;

    if (tid < 32) { sM[tid] = -1e30f; sL[tid] = 0.0f; }
    __syncthreads();

    for (int kt = 0; kt < S_ / TK; kt++) {
        const int k0 = kt * TK;
        floatx4 sp[2][4];
#pragma unroll
        for (int mf = 0; mf < 2; mf++)
#pragma unroll
            for (int nf = 0; nf < 4; nf++) sp[mf][nf] = (floatx4)0.0f;
#pragma unroll
        for (int ks = 0; ks < 8; ks++) {
            int col = wave * DC + ks * 32 + quad * 8;
#pragma unroll
            for (int nf = 0; nf < 4; nf++) {
                int key = k0 + nf * 16 + l16;
                bf16x8 vf = *(const bf16x8*)(vb + ((size_t)b * S_ + key) * D_ + col);
                sp[0][nf] = mfma16(qf[0][ks], vf, sp[0][nf]);
                sp[1][nf] = mfma16(qf[1][ks], vf, sp[1][nf]);
            }
        }
#pragma unroll
        for (int mf = 0; mf < 2; mf++)
#pragma unroll
            for (int nf = 0; nf < 4; nf++)
#pragma unroll
                for (int r = 0; r < 4; r++)
                    sPart[wave][mf * 16 + quad * 4 + r][nf * 16 + l16] = sp[mf][nf][r];
        __syncthreads();

        {
            const int rr = tid >> 3, c0 = (tid & 7) * 8;
            float v[8];
            float mx = -1e30f;
#pragma unroll
            for (int j = 0; j < 8; j++) {
                v[j] = sPart[0][rr][c0 + j] + sPart[1][rr][c0 + j] +
                       sPart[2][rr][c0 + j] + sPart[3][rr][c0 + j];
                mx = fmaxf(mx, v[j]);
            }
            mx = fmaxf(mx, __shfl_xor(mx, 1));
            mx = fmaxf(mx, __shfl_xor(mx, 2));
            mx = fmaxf(mx, __shfl_xor(mx, 4));
            float m_old = sM[rr];
            float m_new = fmaxf(m_old, mx);
            float rsum = 0.0f;
#pragma unroll
            for (int j = 0; j < 8; j++) {
                float p = __expf(v[j] - m_new);
                sP[rr][c0 + j] = (bf16)p;
                rsum += p;
            }
            rsum += __shfl_xor(rsum, 1);
            rsum += __shfl_xor(rsum, 2);
            rsum += __shfl_xor(rsum, 4);
            if ((tid & 7) == 0) {
                float alpha = __expf(m_old - m_new);
                sAlpha[rr] = alpha;
                sM[rr] = m_new;
                sL[rr] = sL[rr] * alpha + rsum;
            }
        }
        __syncthreads();

        float al[2][4];
#pragma unroll
        for (int mf = 0; mf < 2; mf++)
#pragma unroll
            for (int r = 0; r < 4; r++) al[mf][r] = sAlpha[mf * 16 + quad * 4 + r];
#pragma unroll
        for (int mf = 0; mf < 2; mf++)
#pragma unroll
            for (int nf = 0; nf < 16; nf++)
#pragma unroll
                for (int r = 0; r < 4; r++) o[mf][nf][r] *= al[mf][r];

#pragma unroll
        for (int ks2 = 0; ks2 < 2; ks2++) {
            bf16x8 pA[2];
            pA[0] = *(bf16x8*)&sP[l16][ks2 * 32 + quad * 8];
            pA[1] = *(bf16x8*)&sP[16 + l16][ks2 * 32 + quad * 8];
            int key = k0 + ks2 * 32 + quad * 8;
#pragma unroll
            for (int nf = 0; nf < 16; nf++) {
                int d = wave * DC + nf * 16 + l16;
                bf16x8 vtf = *(const bf16x8*)(vtb + ((size_t)b * D_ + d) * S_ + key);
                o[0][nf] = mfma16(pA[0], vtf, o[0][nf]);
                o[1][nf] = mfma16(pA[1], vtf, o[1][nf]);
            }
        }
        __syncthreads();
    }

#pragma unroll
    for (int mf = 0; mf < 2; mf++) {
        float inv[4];
#pragma unroll
        for (int r = 0; r < 4; r++) inv[r] = 1.0f / sL[mf * 16 + quad * 4 + r];
#pragma unroll
        for (int nf = 0; nf < 16; nf++) {
            int d = wave * DC + nf * 16 + l16;
#pragma unroll
            for (int r = 0; r < 4; r++) {
                int row = q0 + mf * 16 + quad * 4 + r;
                out[((size_t)b * S_ + row) * D_ + d] = o[mf][nf][r] * inv[r];
            }
        }
    }
}

// ---------------------------------------------------------------------------
extern "C" void kernel_launch(void* const* d_in, const int* in_sizes, int n_in,
                              void* d_out, int out_size, void* d_ws, size_t ws_size,
                              hipStream_t stream) {
    const float* query = (const float*)d_in[0];
    const float* value = (const float*)d_in[1];
    const float* Wq    = (const float*)d_in[2];
    const float* bq    = (const float*)d_in[3];
    const float* qk_b  = (const float*)d_in[4];
    const float* Wv    = (const float*)d_in[5];
    const float* bv    = (const float*)d_in[6];
    float* out = (float*)d_out;

    const size_t SD = (size_t)S_ * D_;   // 4.19M elems
    const size_t SS = (size_t)S_ * S_;   // 16.8M elems
    const size_t MB = 1024 * 1024;

    char* w = (char*)d_ws;
    bf16* qb = (bf16*)w;                  // 32 MB (scale+bias folded)
    bf16* vb = (bf16*)(w + 32 * MB);      // 32 MB

    if (ws_size >= 224 * MB) {
        // ---- full batched path (256^2 pipelined GEMMs, 32x32 MFMA) ----
        f16* vtb = (f16*)(w + 64 * MB);   // 32 MB [b][d][s]
        f16* Sc  = (f16*)(w + 96 * MB);   // 128 MB [b][q][k]; softmax in place
        bf16* qc  = (bf16*)(w + 96 * MB);   // 32 MB (aliases Sc until written)
        bf16* vc  = (bf16*)(w + 128 * MB);  // 32 MB
        bf16* wqc = (bf16*)(w + 160 * MB);  // 2 MB
        bf16* wvc = (bf16*)(w + 163 * MB);  // 2 MB

        cast_f32_bf16<<<(B_ * SD) / 2048, 256, 0, stream>>>(query, qc);
        cast_f32_bf16<<<(B_ * SD) / 2048, 256, 0, stream>>>(value, vc);
        cast_f32_bf16<<<((size_t)D_ * D_) / 2048, 256, 0, stream>>>(Wq, wqc);
        cast_f32_bf16<<<((size_t)D_ * D_) / 2048, 256, 0, stream>>>(Wv, wvc);

        gemm256<bf16, bf16, true><<<dim3(256, 1, 1), 512, 0, stream>>>(
            qc, wqc, qb, D_, D_, 0, 0, 0, bq, qk_b, 0.125f, 4);
        gemm256<bf16, bf16, true><<<dim3(256, 1, 1), 512, 0, stream>>>(
            vc, wvc, vb, D_, D_, 0, 0, 0, bv, nullptr, 1.0f, 4);

        transpose_v_f16<<<dim3(S_ / 32, D_ / 32, B_), 256, 0, stream>>>(vb, vtb);

        gemm256<bf16, f16, false><<<dim3(256, 1, B_), 512, 0, stream>>>(
            qb, vb, Sc, D_, S_, SD, SD, SS, nullptr, nullptr, 1.0f, 16);

        softmax_inplace_f16<<<B_ * S_, 256, 0, stream>>>(Sc);

        gemm256<f16, float, false><<<dim3(64, 1, B_), 512, 0, stream>>>(
            Sc, vtb, out, S_, D_, SS, (size_t)D_ * S_, SD, nullptr, nullptr, 1.0f, 4);
    } else if (ws_size >= 192 * MB) {
        // ---- per-batch fallback (fp32 scores) ----
        f16*   vtb = (f16*)(w + 64 * MB);
        float* Sc  = (float*)(w + 96 * MB);
        f16*   Pn  = (f16*)(w + 160 * MB);
        bf16*  qc  = (bf16*)(w + 96 * MB);
        bf16*  vc  = (bf16*)(w + 128 * MB);
        bf16*  wqc = (bf16*)(w + 160 * MB);
        bf16*  wvc = (bf16*)(w + 163 * MB);

        cast_f32_bf16<<<(B_ * SD) / 2048, 256, 0, stream>>>(query, qc);
        cast_f32_bf16<<<(B_ * SD) / 2048, 256, 0, stream>>>(value, vc);
        cast_f32_bf16<<<((size_t)D_ * D_) / 2048, 256, 0, stream>>>(Wq, wqc);
        cast_f32_bf16<<<((size_t)D_ * D_) / 2048, 256, 0, stream>>>(Wv, wvc);

        gemm128<bf16, bf16, true><<<dim3(128, 8, 1), 256, 0, stream>>>(
            qc, wqc, qb, D_, D_, 0, 0, 0, bq, qk_b, 0.125f);
        gemm128<bf16, bf16, true><<<dim3(128, 8, 1), 256, 0, stream>>>(
            vc, wvc, vb, D_, D_, 0, 0, 0, bv, nullptr, 1.0f);

        transpose_v_f16<<<dim3(S_ / 32, D_ / 32, B_), 256, 0, stream>>>(vb, vtb);

        for (int b = 0; b < B_; b++) {
            gemm128<bf16, float, false><<<dim3(32, 32, 1), 256, 0, stream>>>(
                qb + b * SD, vb + b * SD, Sc, D_, S_, 0, 0, 0, nullptr, nullptr, 1.0f);
            softmax_row<<<S_, 256, 0, stream>>>(Sc, Pn);
            gemm128<f16, float, false><<<dim3(32, 8, 1), 256, 0, stream>>>(
                Pn, vtb + (size_t)b * D_ * S_, out + b * SD, S_, D_,
                0, 0, 0, nullptr, nullptr, 1.0f);
        }
    } else {
        // ---- flash fallback (96 MB) ----
        bf16* vtb = (bf16*)(w + 64 * MB);
        dim3 pg(16384 / 64, 1024 / 64);
        proj_gemm<<<pg, 256, 0, stream>>>(query, Wq, bq, qk_b, qb, 0.125f);
        proj_gemm<<<pg, 256, 0, stream>>>(value, Wv, bv, nullptr, vb, 1.0f);
        transpose_v<<<dim3(S_ / 32, D_ / 32, B_), 256, 0, stream>>>(vb, vtb);
        flash_attn<<<dim3(S_ / BR, B_), 256, 0, stream>>>(qb, vb, vtb, out);
    }
}

// Round 10
// 553.724 us; speedup vs baseline: 1.1586x; 1.0430x over previous
//
#include <hip/hip_runtime.h>

#define B_ 4
#define S_ 4096
#define D_ 1024

typedef __bf16 bf16;
typedef _Float16 f16;
typedef __attribute__((ext_vector_type(8))) __bf16 bf16x8;
typedef __attribute__((ext_vector_type(8))) _Float16 f16x8;
typedef __attribute__((ext_vector_type(4))) float floatx4;

__device__ inline floatx4 mfma16(bf16x8 a, bf16x8 b, floatx4 c) {
    return __builtin_amdgcn_mfma_f32_16x16x32_bf16(a, b, c, 0, 0, 0);
}
__device__ inline floatx4 mfma_any(bf16x8 a, bf16x8 b, floatx4 c) {
    return __builtin_amdgcn_mfma_f32_16x16x32_bf16(a, b, c, 0, 0, 0);
}
__device__ inline floatx4 mfma_any(f16x8 a, f16x8 b, floatx4 c) {
    return __builtin_amdgcn_mfma_f32_16x16x32_f16(a, b, c, 0, 0, 0);
}

template <typename T> struct vec8_of;
template <> struct vec8_of<bf16> { using type = bf16x8; };
template <> struct vec8_of<f16>  { using type = f16x8; };

__device__ inline bf16x8 cvt8(float4 a, float4 b) {
    bf16x8 h;
    h[0] = (bf16)a.x; h[1] = (bf16)a.y; h[2] = (bf16)a.z; h[3] = (bf16)a.w;
    h[4] = (bf16)b.x; h[5] = (bf16)b.y; h[6] = (bf16)b.z; h[7] = (bf16)b.w;
    return h;
}

// ---------------------------------------------------------------------------
// fused elementwise fp32 -> bf16 cast: blockIdx.z picks stream 0 or 1.
// (round-10: merges the 4 cast launches into 2)
// ---------------------------------------------------------------------------
__global__ __launch_bounds__(256) void cast2_f32_bf16(
    const float* __restrict__ in0, bf16* __restrict__ out0,
    const float* __restrict__ in1, bf16* __restrict__ out1)
{
    const float* in = blockIdx.z ? in1 : in0;
    bf16* out = blockIdx.z ? out1 : out0;
    size_t i = ((size_t)blockIdx.x * 256 + threadIdx.x) * 8;
    float4 a = *(const float4*)(in + i);
    float4 b = *(const float4*)(in + i + 4);
    *(bf16x8*)(out + i) = cvt8(a, b);
}

// ---------------------------------------------------------------------------
// gemm256 (round-6 verified best: 558.5us total, scores 152us, MfmaUtil 37.7%,
// 0 bank conflicts). 256x256 tile, BK=64, 8 waves (2Mx4N), 16x16x32 MFMA.
// Same-phase reads -> barrier -> MFMA (cross-phase register pipelining
// REFUTED twice: rounds 3/4). 32x32x16 MFMA REFUTED (rounds 7-9: bank
// conflicts under every layout tried, or HBM scatter).
// Count discipline (m201 template): steady state keeps 3 half-tiles (6
// loads) in flight; single vmcnt(6) per K-tile at P4:
//   P1: Q11 reads a03(8)+b01(4) ; stage A(t+1)h1 -> buf^1
//   P2: Q12 reads b23(4)
//   P3: Q21 reads a47(8)        ; stage B(t+2)h0 -> buf
//   P4: Q22 no reads            ; stage B(t+2)h1 + A(t+2)h0 -> buf ; vmcnt(6)
// vmcnt(6) retires exactly A(t+1)+B(t+1); FIFO verified from t=0 (prologue
// = tile0 + B(1)h0,h1 + A(1)h0). Loop hand-unrolled x2 => compile-time
// buffer parity. Lifetimes: every LDS overwrite >=1 barrier after last read.
// LDS XOR-swizzle (row&7)<<4 on pre-swizzled global source + ds_read (both
// sides; measured 0 conflicts). Tile order: XCD-bijective chunks -> 4x4
// patch-major (FETCH -33%, time-neutral). setprio(1) around MFMA clusters.
// ---------------------------------------------------------------------------
template <typename TI, typename TO, bool HAS_BIAS>
__global__ __launch_bounds__(512, 2) void gemm256(
    const TI* __restrict__ A, const TI* __restrict__ B, TO* __restrict__ C,
    int K, int ldc, size_t strideA, size_t strideB, size_t strideC,
    const float* __restrict__ bias1, const float* __restrict__ bias2,
    float scale, int tiles_n)
{
    using v8 = typename vec8_of<TI>::type;
    // [buf][half][128 rows x 64 elems] ; 128 KiB total
    __shared__ __align__(16) TI sA[2][2][8192];
    __shared__ __align__(16) TI sB[2][2][8192];

    A += (size_t)blockIdx.z * strideA;
    B += (size_t)blockIdx.z * strideB;
    C += (size_t)blockIdx.z * strideC;

    const int tid = threadIdx.x;
    const int wave = tid >> 6, lane = tid & 63, quad = lane >> 4, l16 = lane & 15;
    const int wm = wave >> 2, wn = wave & 3;

    // XCD-bijective chunking + 4x4 patch-major tile order
    const int gx = gridDim.x;
    const int cpx = gx >> 3;
    const int lid = (blockIdx.x & 7) * cpx + (blockIdx.x >> 3);
    const int p = lid >> 4, w = lid & 15;
    const int pr = tiles_n >> 2;               // patches per tile-row band
    const int Pm = p / pr, Pn = p - Pm * pr;
    const int tm = Pm * 4 + (w >> 2), tn = Pn * 4 + (w & 3);
    const int m0 = tm * 256, n0 = tn * 256;

    const TI* Abase = A + (size_t)m0 * K;
    const TI* Bbase = B + (size_t)n0 * K;

    // staging geometry: 1024 16B chunks per half-tile, 2 per thread.
    // LDS dest linear; global source pre-swizzled (both-sides involution).
    size_t goff[2];
#pragma unroll
    for (int j = 0; j < 2; j++) {
        int idx = j * 512 + tid;
        int dB = idx * 16;
        int L = dB ^ (((dB >> 7) & 7) << 4);
        int r = L >> 7;            // row within half (0..127)
        int c = (L & 127) >> 1;    // elem col (multiple of 8)
        goff[j] = (size_t)r * K + c;
    }
    const int NT = K >> 6;         // even for all K used here
    const size_t halfA = (size_t)128 * K;

    auto stageA = [&](int t, int half, int bufsel) {
#pragma unroll
        for (int j = 0; j < 2; j++) {
            int idx = j * 512 + tid;
            __builtin_amdgcn_global_load_lds(
                (const __attribute__((address_space(1))) void*)(
                    Abase + (size_t)t * 64 + (half ? halfA : 0) + goff[j]),
                (__attribute__((address_space(3))) void*)(sA[bufsel][half] + idx * 8),
                16, 0, 0);
        }
    };
    auto stageB = [&](int t, int half, int bufsel) {
#pragma unroll
        for (int j = 0; j < 2; j++) {
            int idx = j * 512 + tid;
            __builtin_amdgcn_global_load_lds(
                (const __attribute__((address_space(1))) void*)(
                    Bbase + (size_t)t * 64 + (half ? halfA : 0) + goff[j]),
                (__attribute__((address_space(3))) void*)(sB[bufsel][half] + idx * 8),
                16, 0, 0);
        }
    };
    // fragment reads (swizzled). A-half = wm; B-half = wn>>1.
    auto rdA = [&](int buf, int i, int q) -> v8 {
        int row = i * 16 + l16;
        int byte = (row * 128 + q * 64 + quad * 16) ^ ((row & 7) << 4);
        return *(const v8*)((const char*)(sA[buf][wm]) + byte);
    };
    auto rdB = [&](int buf, int j, int q) -> v8 {
        int row = (wn & 1) * 64 + j * 16 + l16;
        int byte = (row * 128 + q * 64 + quad * 16) ^ ((row & 7) << 4);
        return *(const v8*)((const char*)(sB[buf][wn >> 1]) + byte);
    };

    floatx4 acc[8][4];
#pragma unroll
    for (int i = 0; i < 8; i++)
#pragma unroll
        for (int j = 0; j < 4; j++) acc[i][j] = (floatx4)0.0f;

    // prologue: tile0 fully (4 half-tiles), then B(1)h0,h1 + A(1)h0
    // (3 half-tiles, steady order). vmcnt(6) leaves exactly those 3 in
    // flight; tile 0's P1 stages A(1)h1.
    {
        int t1 = (1 < NT) ? 1 : 0;
        stageA(0, 0, 0); stageA(0, 1, 0);
        stageB(0, 0, 0); stageB(0, 1, 0);
        stageB(t1, 0, 1); stageB(t1, 1, 1);
        stageA(t1, 0, 1);
        asm volatile("s_waitcnt vmcnt(6)" ::: "memory");
        __builtin_amdgcn_s_barrier();
    }

    v8 a[8], b0[4], b1[4];
    for (int u = 0; u < NT; u += 2) {
#pragma unroll
        for (int half_it = 0; half_it < 2; half_it++) {
            const int t = u + half_it;
            const int buf = half_it;                        // compile-time
            const int tA = (t + 1 < NT) ? t + 1 : NT - 1;   // clamp: dead restage
            const int tB = (t + 2 < NT) ? t + 2 : NT - 1;

            // ---- phase 1: Q11 (m0-3)x(n0-1) ; reads a03(t), b01(t) ;
            //      stage A(t+1)h1 -> buf^1 (A(t+1)h0 staged at t-1.P4) ----
#pragma unroll
            for (int i = 0; i < 4; i++) { a[2 * i] = rdA(buf, i, 0); a[2 * i + 1] = rdA(buf, i, 1); }
#pragma unroll
            for (int j = 0; j < 2; j++) { b0[2 * j] = rdB(buf, j, 0); b0[2 * j + 1] = rdB(buf, j, 1); }
            stageA(tA, 1, buf ^ 1);
            __builtin_amdgcn_s_barrier();
            __builtin_amdgcn_s_setprio(1);
#pragma unroll
            for (int i = 0; i < 4; i++)
#pragma unroll
                for (int j = 0; j < 2; j++) {
                    acc[i][j] = mfma_any(a[2 * i], b0[2 * j], acc[i][j]);
                    acc[i][j] = mfma_any(a[2 * i + 1], b0[2 * j + 1], acc[i][j]);
                }
            __builtin_amdgcn_s_setprio(0);
            __builtin_amdgcn_s_barrier();

            // ---- phase 2: Q12 (m0-3)x(n2-3) ; reads b23(t) ----
#pragma unroll
            for (int j = 0; j < 2; j++) { b1[2 * j] = rdB(buf, 2 + j, 0); b1[2 * j + 1] = rdB(buf, 2 + j, 1); }
            __builtin_amdgcn_s_barrier();
            __builtin_amdgcn_s_setprio(1);
#pragma unroll
            for (int i = 0; i < 4; i++)
#pragma unroll
                for (int j = 0; j < 2; j++) {
                    acc[i][2 + j] = mfma_any(a[2 * i], b1[2 * j], acc[i][2 + j]);
                    acc[i][2 + j] = mfma_any(a[2 * i + 1], b1[2 * j + 1], acc[i][2 + j]);
                }
            __builtin_amdgcn_s_setprio(0);
            __builtin_amdgcn_s_barrier();

            // ---- phase 3: Q21 (m4-7)x(n2-3) ; reads a47(t) ;
            //      stage B(t+2)h0 -> buf (B(t) died at P2) ----
#pragma unroll
            for (int i = 0; i < 4; i++) { a[2 * i] = rdA(buf, 4 + i, 0); a[2 * i + 1] = rdA(buf, 4 + i, 1); }
            stageB(tB, 0, buf);
            __builtin_amdgcn_s_barrier();
            __builtin_amdgcn_s_setprio(1);
#pragma unroll
            for (int i = 0; i < 4; i++)
#pragma unroll
                for (int j = 0; j < 2; j++) {
                    acc[4 + i][2 + j] = mfma_any(a[2 * i], b1[2 * j], acc[4 + i][2 + j]);
                    acc[4 + i][2 + j] = mfma_any(a[2 * i + 1], b1[2 * j + 1], acc[4 + i][2 + j]);
                }
            __builtin_amdgcn_s_setprio(0);
            __builtin_amdgcn_s_barrier();

            // ---- phase 4: Q22 (m4-7)x(n0-1) ; no reads ;
            //      stage B(t+2)h1 + A(t+2)h0 -> buf ; vmcnt(6) ----
            stageB(tB, 1, buf);
            stageA(tB, 0, buf);
            asm volatile("s_waitcnt vmcnt(6)" ::: "memory");
            __builtin_amdgcn_s_barrier();
            __builtin_amdgcn_s_setprio(1);
#pragma unroll
            for (int i = 0; i < 4; i++)
#pragma unroll
                for (int j = 0; j < 2; j++) {
                    acc[4 + i][j] = mfma_any(a[2 * i], b0[2 * j], acc[4 + i][j]);
                    acc[4 + i][j] = mfma_any(a[2 * i + 1], b0[2 * j + 1], acc[4 + i][j]);
                }
            __builtin_amdgcn_s_setprio(0);
            __builtin_amdgcn_s_barrier();
        }
    }

    // epilogue
#pragma unroll
    for (int mf = 0; mf < 8; mf++)
#pragma unroll
        for (int nf = 0; nf < 4; nf++) {
            int col = n0 + wn * 64 + nf * 16 + l16;
            float badd = 0.0f;
            if (HAS_BIAS) {
                badd = bias1[col];
                if (bias2) badd += bias2[col];
            }
#pragma unroll
            for (int r = 0; r < 4; r++) {
                int row = m0 + wm * 128 + mf * 16 + quad * 4 + r;
                float v = acc[mf][nf][r];
                if (HAS_BIAS) v = (v + badd) * scale;
                C[(size_t)row * ldc + col] = (TO)v;
            }
        }
}

// ---------------------------------------------------------------------------
// m97-style GEMM (kept for fallback paths)
// ---------------------------------------------------------------------------
template <typename TI, typename TO, bool HAS_BIAS>
__global__ __launch_bounds__(256) void gemm128(
    const TI* __restrict__ A, const TI* __restrict__ B, TO* __restrict__ C,
    int K, int ldc, size_t strideA, size_t strideB, size_t strideC,
    const float* __restrict__ bias1, const float* __restrict__ bias2, float scale)
{
    using v8 = typename vec8_of<TI>::type;
    __shared__ TI sA[2 * 128 * 32];
    __shared__ TI sB[2 * 128 * 32];
    A += (size_t)blockIdx.z * strideA;
    B += (size_t)blockIdx.z * strideB;
    C += (size_t)blockIdx.z * strideC;

    const int tid = threadIdx.x;
    const int wave = tid >> 6, lane = tid & 63, quad = lane >> 4, l16 = lane & 15;
    const int m0 = blockIdx.x * 128, n0 = blockIdx.y * 128;
    const int wr = (wave >> 1) * 64, wc = (wave & 1) * 64;

    floatx4 acc[4][4];
#pragma unroll
    for (int i = 0; i < 4; i++)
#pragma unroll
        for (int j = 0; j < 4; j++) acc[i][j] = (floatx4)0.0f;

    for (int k0 = 0; k0 < K; k0 += 64) {
#pragma unroll
        for (int s = 0; s < 2; s++) {
#pragma unroll
            for (int j = 0; j < 2; j++) {
                int idx = j * 256 + tid;
                int r = idx >> 2, c = (idx & 3) * 8;
                __builtin_amdgcn_global_load_lds(
                    (const __attribute__((address_space(1))) void*)(A + (size_t)(m0 + r) * K + k0 + s * 32 + c),
                    (__attribute__((address_space(3))) void*)(sA + s * 4096 + idx * 8), 16, 0, 0);
                __builtin_amdgcn_global_load_lds(
                    (const __attribute__((address_space(1))) void*)(B + (size_t)(n0 + r) * K + k0 + s * 32 + c),
                    (__attribute__((address_space(3))) void*)(sB + s * 4096 + idx * 8), 16, 0, 0);
            }
        }
        __syncthreads();
#pragma unroll
        for (int s = 0; s < 2; s++) {
            v8 af[4], bfv[4];
#pragma unroll
            for (int i = 0; i < 4; i++) {
                af[i]  = *(const v8*)&sA[s * 4096 + (wr + i * 16 + l16) * 32 + quad * 8];
                bfv[i] = *(const v8*)&sB[s * 4096 + (wc + i * 16 + l16) * 32 + quad * 8];
            }
#pragma unroll
            for (int mf = 0; mf < 4; mf++)
#pragma unroll
                for (int nf = 0; nf < 4; nf++)
                    acc[mf][nf] = mfma_any(af[mf], bfv[nf], acc[mf][nf]);
        }
        __syncthreads();
    }

#pragma unroll
    for (int mf = 0; mf < 4; mf++)
#pragma unroll
        for (int nf = 0; nf < 4; nf++) {
            int col = n0 + wc + nf * 16 + l16;
            float badd = 0.0f;
            if (HAS_BIAS) {
                badd = bias1[col];
                if (bias2) badd += bias2[col];
            }
#pragma unroll
            for (int r = 0; r < 4; r++) {
                int row = m0 + wr + mf * 16 + quad * 4 + r;
                float v = acc[mf][nf][r];
                if (HAS_BIAS) v = (v + badd) * scale;
                C[(size_t)row * ldc + col] = (TO)v;
            }
        }
}

// ---------------------------------------------------------------------------
// transposes: vb [b][s][d] -> vtb [b][d][s]
// ---------------------------------------------------------------------------
__global__ __launch_bounds__(256) void transpose_v(
    const bf16* __restrict__ vb, bf16* __restrict__ vtb)
{
    __shared__ bf16 tile[32][33];
    const int b = blockIdx.z;
    const int s0 = blockIdx.x * 32, d0 = blockIdx.y * 32;
    const int tr = threadIdx.x >> 5;
    const int tc = threadIdx.x & 31;
#pragma unroll
    for (int k = 0; k < 4; k++) {
        int r = tr + k * 8;
        tile[r][tc] = vb[((size_t)b * S_ + s0 + r) * D_ + d0 + tc];
    }
    __syncthreads();
#pragma unroll
    for (int k = 0; k < 4; k++) {
        int r = tr + k * 8;
        vtb[((size_t)b * D_ + d0 + r) * S_ + s0 + tc] = tile[tc][r];
    }
}

__global__ __launch_bounds__(256) void transpose_v_f16(
    const bf16* __restrict__ vb, f16* __restrict__ vtb)
{
    __shared__ bf16 tile[32][33];
    const int b = blockIdx.z;
    const int s0 = blockIdx.x * 32, d0 = blockIdx.y * 32;
    const int tr = threadIdx.x >> 5;
    const int tc = threadIdx.x & 31;
#pragma unroll
    for (int k = 0; k < 4; k++) {
        int r = tr + k * 8;
        tile[r][tc] = vb[((size_t)b * S_ + s0 + r) * D_ + d0 + tc];
    }
    __syncthreads();
#pragma unroll
    for (int k = 0; k < 4; k++) {
        int r = tr + k * 8;
        vtb[((size_t)b * D_ + d0 + r) * S_ + s0 + tc] = (f16)(float)tile[tc][r];
    }
}

// ---------------------------------------------------------------------------
// softmax over one 4096-row of f16 scores, in place (normalized f16 out)
// ---------------------------------------------------------------------------
__global__ __launch_bounds__(256) void softmax_inplace_f16(f16* __restrict__ Sc)
{
    f16* row = Sc + (size_t)blockIdx.x * S_;
    const int tid = threadIdx.x, wave = tid >> 6, lane = tid & 63;
    __shared__ float redm[4], redl[4];

    f16x8 a = *(const f16x8*)(row + tid * 16);
    f16x8 b = *(const f16x8*)(row + tid * 16 + 8);
    float v[16];
#pragma unroll
    for (int j = 0; j < 8; j++) { v[j] = (float)a[j]; v[8 + j] = (float)b[j]; }

    float m = -1e30f;
#pragma unroll
    for (int j = 0; j < 16; j++) m = fmaxf(m, v[j]);
#pragma unroll
    for (int off = 32; off; off >>= 1) m = fmaxf(m, __shfl_xor(m, off));
    if (lane == 0) redm[wave] = m;
    __syncthreads();
    m = fmaxf(fmaxf(redm[0], redm[1]), fmaxf(redm[2], redm[3]));

    float s = 0.0f;
#pragma unroll
    for (int j = 0; j < 16; j++) { v[j] = __expf(v[j] - m); s += v[j]; }
#pragma unroll
    for (int off = 32; off; off >>= 1) s += __shfl_xor(s, off);
    if (lane == 0) redl[wave] = s;
    __syncthreads();
    s = redl[0] + redl[1] + redl[2] + redl[3];
    float inv = 1.0f / s;

#pragma unroll
    for (int j = 0; j < 8; j++) { a[j] = (f16)(v[j] * inv); b[j] = (f16)(v[8 + j] * inv); }
    *(f16x8*)(row + tid * 16) = a;
    *(f16x8*)(row + tid * 16 + 8) = b;
}

// ---------------------------------------------------------------------------
// softmax over one fp32 score row -> normalized fp16 (per-batch fallback)
// ---------------------------------------------------------------------------
__global__ __launch_bounds__(256) void softmax_row(
    const float* __restrict__ Sc, f16* __restrict__ P)
{
    const int q = blockIdx.x;
    const float* row = Sc + (size_t)q * S_;
    f16* prow = P + (size_t)q * S_;
    const int tid = threadIdx.x, wave = tid >> 6, lane = tid & 63;

    float4 v[4];
#pragma unroll
    for (int i = 0; i < 4; i++) v[i] = *(const float4*)(row + tid * 16 + i * 4);

    float m = -1e30f;
#pragma unroll
    for (int i = 0; i < 4; i++)
        m = fmaxf(m, fmaxf(fmaxf(v[i].x, v[i].y), fmaxf(v[i].z, v[i].w)));
#pragma unroll
    for (int off = 32; off; off >>= 1) m = fmaxf(m, __shfl_xor(m, off));
    __shared__ float redm[4], redl[4];
    if (lane == 0) redm[wave] = m;
    __syncthreads();
    m = fmaxf(fmaxf(redm[0], redm[1]), fmaxf(redm[2], redm[3]));

    float p[16];
    float s = 0.0f;
#pragma unroll
    for (int i = 0; i < 4; i++) {
        p[i * 4 + 0] = __expf(v[i].x - m);
        p[i * 4 + 1] = __expf(v[i].y - m);
        p[i * 4 + 2] = __expf(v[i].z - m);
        p[i * 4 + 3] = __expf(v[i].w - m);
        s += p[i * 4] + p[i * 4 + 1] + p[i * 4 + 2] + p[i * 4 + 3];
    }
#pragma unroll
    for (int off = 32; off; off >>= 1) s += __shfl_xor(s, off);
    if (lane == 0) redl[wave] = s;
    __syncthreads();
    s = redl[0] + redl[1] + redl[2] + redl[3];
    float inv = 1.0f / s;

    f16x8 o0, o1;
#pragma unroll
    for (int j = 0; j < 8; j++) {
        o0[j] = (f16)(p[j] * inv);
        o1[j] = (f16)(p[8 + j] * inv);
    }
    *(f16x8*)(prow + tid * 16) = o0;
    *(f16x8*)(prow + tid * 16 + 8) = o1;
}

// ---------------------------------------------------------------------------
// legacy fp32-input proj (flash fallback only)
// ---------------------------------------------------------------------------
#define SSTR 40
__global__ __launch_bounds__(256) void proj_gemm(
    const float* __restrict__ A, const float* __restrict__ W,
    const float* __restrict__ bias1, const float* __restrict__ bias2,
    bf16* __restrict__ C, float scale)
{
    __shared__ bf16 sA[64 * SSTR];
    __shared__ bf16 sB[64 * SSTR];
    const int tid = threadIdx.x;
    const int wave = tid >> 6, lane = tid & 63, quad = lane >> 4, l16 = lane & 15;
    const int m0 = blockIdx.x * 64, n0 = blockIdx.y * 64;
    const int wr = (wave >> 1) * 32, wc = (wave & 1) * 32;
    const int lr = tid >> 2;
    const int lc = (tid & 3) * 8;

    floatx4 acc[2][2];
#pragma unroll
    for (int i = 0; i < 2; i++)
#pragma unroll
        for (int j = 0; j < 2; j++) acc[i][j] = (floatx4)0.0f;

    for (int k0 = 0; k0 < 1024; k0 += 32) {
        const float* ga = A + (size_t)(m0 + lr) * 1024 + k0 + lc;
        const float* gw = W + (size_t)(n0 + lr) * 1024 + k0 + lc;
        float4 a0 = *(const float4*)ga;
        float4 a1 = *(const float4*)(ga + 4);
        float4 w0 = *(const float4*)gw;
        float4 w1 = *(const float4*)(gw + 4);
        *(bf16x8*)&sA[lr * SSTR + lc] = cvt8(a0, a1);
        *(bf16x8*)&sB[lr * SSTR + lc] = cvt8(w0, w1);
        __syncthreads();
        bf16x8 af[2], bfv[2];
        af[0]  = *(bf16x8*)&sA[(wr + l16) * SSTR + quad * 8];
        af[1]  = *(bf16x8*)&sA[(wr + 16 + l16) * SSTR + quad * 8];
        bfv[0] = *(bf16x8*)&sB[(wc + l16) * SSTR + quad * 8];
        bfv[1] = *(bf16x8*)&sB[(wc + 16 + l16) * SSTR + quad * 8];
#pragma unroll
        for (int mf = 0; mf < 2; mf++)
#pragma unroll
            for (int nf = 0; nf < 2; nf++)
                acc[mf][nf] = mfma16(af[mf], bfv[nf], acc[mf][nf]);
        __syncthreads();
    }
#pragma unroll
    for (int mf = 0; mf < 2; mf++)
#pragma unroll
        for (int nf = 0; nf < 2; nf++) {
            int col = n0 + wc + nf * 16 + l16;
            float bsum = bias1[col] + (bias2 ? bias2[col] : 0.0f);
#pragma unroll
            for (int r = 0; r < 4; r++) {
                int row = m0 + wr + mf * 16 + quad * 4 + r;
                C[(size_t)row * 1024 + col] = (bf16)((acc[mf][nf][r] + bsum) * scale);
            }
        }
}

// ---------------------------------------------------------------------------
// flash fallback (only if ws < 192MB)
// ---------------------------------------------------------------------------
#define BR 32
#define TK 64
#define DC 256
__global__ __launch_bounds__(256, 2) void flash_attn(
    const bf16* __restrict__ qb, const bf16* __restrict__ vb,
    const bf16* __restrict__ vtb, float* __restrict__ out)
{
    __shared__ float sPart[4][32][65];
    __shared__ bf16 sP[32][72];
    __shared__ float sM[32], sL[32], sAlpha[32];

    const int tid = threadIdx.x;
    const int wave = tid >> 6, lane = tid & 63, quad = lane >> 4, l16 = lane & 15;
    const int b = blockIdx.y, q0 = blockIdx.x * BR;

    bf16x8 qf[2][8];
#pragma unroll
    for (int mf = 0; mf < 2; mf++)
#pragma unroll
        for (int ks = 0; ks < 8; ks++) {
            int row = q0 + mf * 16 + l16;
            int col = wave * DC + ks * 32 + quad * 8;
            qf[mf][ks] = *(const bf16x8*)(qb + ((size_t)b * S_ + row) * D_ + col);
        }

    floatx4 o[2][16];
#pragma unroll
    for (int mf = 0; mf < 2; mf++)
#pragma unroll
        for (int nf = 0; nf < 16; nf++) o[mf][nf] = (floatx4)0.0f;

    if (tid < 32) { sM[tid] = -1e30f; sL[tid] = 0.0f; }
    __syncthreads();

    for (int kt = 0; kt < S_ / TK; kt++) {
        const int k0 = kt * TK;
        floatx4 sp[2][4];
#pragma unroll
        for (int mf = 0; mf < 2; mf++)
#pragma unroll
            for (int nf = 0; nf < 4; nf++) sp[mf][nf] = (floatx4)0.0f;
#pragma unroll
        for (int ks = 0; ks < 8; ks++) {
            int col = wave * DC + ks * 32 + quad * 8;
#pragma unroll
            for (int nf = 0; nf < 4; nf++) {
                int key = k0 + nf * 16 + l16;
                bf16x8 vf = *(const bf16x8*)(vb + ((size_t)b * S_ + key) * D_ + col);
                sp[0][nf] = mfma16(qf[0][ks], vf, sp[0][nf]);
                sp[1][nf] = mfma16(qf[1][ks], vf, sp[1][nf]);
            }
        }
#pragma unroll
        for (int mf = 0; mf < 2; mf++)
#pragma unroll
            for (int nf = 0; nf < 4; nf++)
#pragma unroll
                for (int r = 0; r < 4; r++)
                    sPart[wave][mf * 16 + quad * 4 + r][nf * 16 + l16] = sp[mf][nf][r];
        __syncthreads();

        {
            const int rr = tid >> 3, c0 = (tid & 7) * 8;
            float v[8];
            float mx = -1e30f;
#pragma unroll
            for (int j = 0; j < 8; j++) {
                v[j] = sPart[0][rr][c0 + j] + sPart[1][rr][c0 + j] +
                       sPart[2][rr][c0 + j] + sPart[3][rr][c0 + j];
                mx = fmaxf(mx, v[j]);
            }
            mx = fmaxf(mx, __shfl_xor(mx, 1));
            mx = fmaxf(mx, __shfl_xor(mx, 2));
            mx = fmaxf(mx, __shfl_xor(mx, 4));
            float m_old = sM[rr];
            float m_new = fmaxf(m_old, mx);
            float rsum = 0.0f;
#pragma unroll
            for (int j = 0; j < 8; j++) {
                float p = __expf(v[j] - m_new);
                sP[rr][c0 + j] = (bf16)p;
                rsum += p;
            }
            rsum += __shfl_xor(rsum, 1);
            rsum += __shfl_xor(rsum, 2);
            rsum += __shfl_xor(rsum, 4);
            if ((tid & 7) == 0) {
                float alpha = __expf(m_old - m_new);
                sAlpha[rr] = alpha;
                sM[rr] = m_new;
                sL[rr] = sL[rr] * alpha + rsum;
            }
        }
        __syncthreads();

        float al[2][4];
#pragma unroll
        for (int mf = 0; mf < 2; mf++)
#pragma unroll
            for (int r = 0; r < 4; r++) al[mf][r] = sAlpha[mf * 16 + quad * 4 + r];
#pragma unroll
        for (int mf = 0; mf < 2; mf++)
#pragma unroll
            for (int nf = 0; nf < 16; nf++)
#pragma unroll
                for (int r = 0; r < 4; r++) o[mf][nf][r] *= al[mf][r];

#pragma unroll
        for (int ks2 = 0; ks2 < 2; ks2++) {
            bf16x8 pA[2];
            pA[0] = *(bf16x8*)&sP[l16][ks2 * 32 + quad * 8];
            pA[1] = *(bf16x8*)&sP[16 + l16][ks2 * 32 + quad * 8];
            int key = k0 + ks2 * 32 + quad * 8;
#pragma unroll
            for (int nf = 0; nf < 16; nf++) {
                int d = wave * DC + nf * 16 + l16;
                bf16x8 vtf = *(const bf16x8*)(vtb + ((size_t)b * D_ + d) * S_ + key);
                o[0][nf] = mfma16(pA[0], vtf, o[0][nf]);
                o[1][nf] = mfma16(pA[1], vtf, o[1][nf]);
            }
        }
        __syncthreads();
    }

#pragma unroll
    for (int mf = 0; mf < 2; mf++) {
        float inv[4];
#pragma unroll
        for (int r = 0; r < 4; r++) inv[r] = 1.0f / sL[mf * 16 + quad * 4 + r];
#pragma unroll
        for (int nf = 0; nf < 16; nf++) {
            int d = wave * DC + nf * 16 + l16;
#pragma unroll
            for (int r = 0; r < 4; r++) {
                int row = q0 + mf * 16 + quad * 4 + r;
                out[((size_t)b * S_ + row) * D_ + d] = o[mf][nf][r] * inv[r];
            }
        }
    }
}

// ---------------------------------------------------------------------------
extern "C" void kernel_launch(void* const* d_in, const int* in_sizes, int n_in,
                              void* d_out, int out_size, void* d_ws, size_t ws_size,
                              hipStream_t stream) {
    const float* query = (const float*)d_in[0];
    const float* value = (const float*)d_in[1];
    const float* Wq    = (const float*)d_in[2];
    const float* bq    = (const float*)d_in[3];
    const float* qk_b  = (const float*)d_in[4];
    const float* Wv    = (const float*)d_in[5];
    const float* bv    = (const float*)d_in[6];
    float* out = (float*)d_out;

    const size_t SD = (size_t)S_ * D_;   // 4.19M elems
    const size_t SS = (size_t)S_ * S_;   // 16.8M elems
    const size_t MB = 1024 * 1024;

    char* w = (char*)d_ws;
    bf16* qb = (bf16*)w;                  // 32 MB (scale+bias folded)
    bf16* vb = (bf16*)(w + 32 * MB);      // 32 MB

    if (ws_size >= 224 * MB) {
        // ---- full batched path (round-6 verified 256^2 pipelined GEMMs) ----
        f16* vtb = (f16*)(w + 64 * MB);   // 32 MB [b][d][s]
        f16* Sc  = (f16*)(w + 96 * MB);   // 128 MB [b][q][k]; softmax in place
        bf16* qc  = (bf16*)(w + 96 * MB);   // 32 MB (aliases Sc until written)
        bf16* vc  = (bf16*)(w + 128 * MB);  // 32 MB
        bf16* wqc = (bf16*)(w + 160 * MB);  // 2 MB
        bf16* wvc = (bf16*)(w + 163 * MB);  // 2 MB

        // fused casts: q+v in one launch, Wq+Wv in one launch
        cast2_f32_bf16<<<dim3((B_ * SD) / 2048, 1, 2), 256, 0, stream>>>(
            query, qc, value, vc);
        cast2_f32_bf16<<<dim3(((size_t)D_ * D_) / 2048, 1, 2), 256, 0, stream>>>(
            Wq, wqc, Wv, wvc);

        // projections: [16384 x 1024] = [16384 x 1024] . [1024 x 1024]^T
        gemm256<bf16, bf16, true><<<dim3(256, 1, 1), 512, 0, stream>>>(
            qc, wqc, qb, D_, D_, 0, 0, 0, bq, qk_b, 0.125f, 4);
        gemm256<bf16, bf16, true><<<dim3(256, 1, 1), 512, 0, stream>>>(
            vc, wvc, vb, D_, D_, 0, 0, 0, bv, nullptr, 1.0f, 4);

        transpose_v_f16<<<dim3(S_ / 32, D_ / 32, B_), 256, 0, stream>>>(vb, vtb);

        // scores: Sc[b][q][k] = qb[b][q][:] . vb[b][k][:]  (16x16 tiles/batch)
        gemm256<bf16, f16, false><<<dim3(256, 1, B_), 512, 0, stream>>>(
            qb, vb, Sc, D_, S_, SD, SD, SS, nullptr, nullptr, 1.0f, 16);

        softmax_inplace_f16<<<B_ * S_, 256, 0, stream>>>(Sc);

        // O: out[b][q][d] = P[b][q][:] . vtb[b][d][:]  (16x4 tiles/batch)
        gemm256<f16, float, false><<<dim3(64, 1, B_), 512, 0, stream>>>(
            Sc, vtb, out, S_, D_, SS, (size_t)D_ * S_, SD, nullptr, nullptr, 1.0f, 4);
    } else if (ws_size >= 192 * MB) {
        // ---- per-batch fallback (fp32 scores) ----
        f16*   vtb = (f16*)(w + 64 * MB);
        float* Sc  = (float*)(w + 96 * MB);
        f16*   Pn  = (f16*)(w + 160 * MB);
        bf16*  qc  = (bf16*)(w + 96 * MB);
        bf16*  vc  = (bf16*)(w + 128 * MB);
        bf16*  wqc = (bf16*)(w + 160 * MB);
        bf16*  wvc = (bf16*)(w + 163 * MB);

        cast2_f32_bf16<<<dim3((B_ * SD) / 2048, 1, 2), 256, 0, stream>>>(
            query, qc, value, vc);
        cast2_f32_bf16<<<dim3(((size_t)D_ * D_) / 2048, 1, 2), 256, 0, stream>>>(
            Wq, wqc, Wv, wvc);

        gemm128<bf16, bf16, true><<<dim3(128, 8, 1), 256, 0, stream>>>(
            qc, wqc, qb, D_, D_, 0, 0, 0, bq, qk_b, 0.125f);
        gemm128<bf16, bf16, true><<<dim3(128, 8, 1), 256, 0, stream>>>(
            vc, wvc, vb, D_, D_, 0, 0, 0, bv, nullptr, 1.0f);

        transpose_v_f16<<<dim3(S_ / 32, D_ / 32, B_), 256, 0, stream>>>(vb, vtb);

        for (int b = 0; b < B_; b++) {
            gemm128<bf16, float, false><<<dim3(32, 32, 1), 256, 0, stream>>>(
                qb + b * SD, vb + b * SD, Sc, D_, S_, 0, 0, 0, nullptr, nullptr, 1.0f);
            softmax_row<<<S_, 256, 0, stream>>>(Sc, Pn);
            gemm128<f16, float, false><<<dim3(32, 8, 1), 256, 0, stream>>>(
                Pn, vtb + (size_t)b * D_ * S_, out + b * SD, S_, D_,
                0, 0, 0, nullptr, nullptr, 1.0f);
        }
    } else {
        // ---- flash fallback (96 MB) ----
        bf16* vtb = (bf16*)(w + 64 * MB);
        dim3 pg(16384 / 64, 1024 / 64);
        proj_gemm<<<pg, 256, 0, stream>>>(query, Wq, bq, qk_b, qb, 0.125f);
        proj_gemm<<<pg, 256, 0, stream>>>(value, Wv, bv, nullptr, vb, 1.0f);
        transpose_v<<<dim3(S_ / 32, D_ / 32, B_), 256, 0, stream>>>(vb, vtb);
        flash_attn<<<dim3(S_ / BR, B_), 256, 0, stream>>>(qb, vb, vtb, out);
    }
}

// Round 11
// 552.374 us; speedup vs baseline: 1.1615x; 1.0024x over previous
//
#include <hip/hip_runtime.h>

#define B_ 4
#define S_ 4096
#define D_ 1024

typedef __bf16 bf16;
typedef _Float16 f16;
typedef __attribute__((ext_vector_type(8))) __bf16 bf16x8;
typedef __attribute__((ext_vector_type(8))) _Float16 f16x8;
typedef __attribute__((ext_vector_type(4))) float floatx4;

__device__ inline floatx4 mfma16(bf16x8 a, bf16x8 b, floatx4 c) {
    return __builtin_amdgcn_mfma_f32_16x16x32_bf16(a, b, c, 0, 0, 0);
}
__device__ inline floatx4 mfma_any(bf16x8 a, bf16x8 b, floatx4 c) {
    return __builtin_amdgcn_mfma_f32_16x16x32_bf16(a, b, c, 0, 0, 0);
}
__device__ inline floatx4 mfma_any(f16x8 a, f16x8 b, floatx4 c) {
    return __builtin_amdgcn_mfma_f32_16x16x32_f16(a, b, c, 0, 0, 0);
}

template <typename T> struct vec8_of;
template <> struct vec8_of<bf16> { using type = bf16x8; };
template <> struct vec8_of<f16>  { using type = f16x8; };

__device__ inline bf16x8 cvt8(float4 a, float4 b) {
    bf16x8 h;
    h[0] = (bf16)a.x; h[1] = (bf16)a.y; h[2] = (bf16)a.z; h[3] = (bf16)a.w;
    h[4] = (bf16)b.x; h[5] = (bf16)b.y; h[6] = (bf16)b.z; h[7] = (bf16)b.w;
    return h;
}

// ---------------------------------------------------------------------------
// fused elementwise fp32 -> bf16 cast: blockIdx.z picks stream 0 or 1.
// ---------------------------------------------------------------------------
__global__ __launch_bounds__(256) void cast2_f32_bf16(
    const float* __restrict__ in0, bf16* __restrict__ out0,
    const float* __restrict__ in1, bf16* __restrict__ out1)
{
    const float* in = blockIdx.z ? in1 : in0;
    bf16* out = blockIdx.z ? out1 : out0;
    size_t i = ((size_t)blockIdx.x * 256 + threadIdx.x) * 8;
    float4 a = *(const float4*)(in + i);
    float4 b = *(const float4*)(in + i + 4);
    *(bf16x8*)(out + i) = cvt8(a, b);
}

// ---------------------------------------------------------------------------
// gemm256 (round-6 verified best; see round-10 header for the full ledger:
// same-phase reads, vmcnt(6) count discipline, compile-time buffer parity,
// both-sides (row&7)<<4 LDS swizzle [0 conflicts], patch-major+XCD order,
// setprio. Cross-phase reads REFUTED x2; 32x32 MFMA REFUTED x3.)
// ---------------------------------------------------------------------------
template <typename TI, typename TO, bool HAS_BIAS>
__global__ __launch_bounds__(512, 2) void gemm256(
    const TI* __restrict__ A, const TI* __restrict__ B, TO* __restrict__ C,
    int K, int ldc, size_t strideA, size_t strideB, size_t strideC,
    const float* __restrict__ bias1, const float* __restrict__ bias2,
    float scale, int tiles_n)
{
    using v8 = typename vec8_of<TI>::type;
    __shared__ __align__(16) TI sA[2][2][8192];
    __shared__ __align__(16) TI sB[2][2][8192];

    A += (size_t)blockIdx.z * strideA;
    B += (size_t)blockIdx.z * strideB;
    C += (size_t)blockIdx.z * strideC;

    const int tid = threadIdx.x;
    const int wave = tid >> 6, lane = tid & 63, quad = lane >> 4, l16 = lane & 15;
    const int wm = wave >> 2, wn = wave & 3;

    const int gx = gridDim.x;
    const int cpx = gx >> 3;
    const int lid = (blockIdx.x & 7) * cpx + (blockIdx.x >> 3);
    const int p = lid >> 4, w = lid & 15;
    const int pr = tiles_n >> 2;
    const int Pm = p / pr, Pn = p - Pm * pr;
    const int tm = Pm * 4 + (w >> 2), tn = Pn * 4 + (w & 3);
    const int m0 = tm * 256, n0 = tn * 256;

    const TI* Abase = A + (size_t)m0 * K;
    const TI* Bbase = B + (size_t)n0 * K;

    size_t goff[2];
#pragma unroll
    for (int j = 0; j < 2; j++) {
        int idx = j * 512 + tid;
        int dB = idx * 16;
        int L = dB ^ (((dB >> 7) & 7) << 4);
        int r = L >> 7;
        int c = (L & 127) >> 1;
        goff[j] = (size_t)r * K + c;
    }
    const int NT = K >> 6;
    const size_t halfA = (size_t)128 * K;

    auto stageA = [&](int t, int half, int bufsel) {
#pragma unroll
        for (int j = 0; j < 2; j++) {
            int idx = j * 512 + tid;
            __builtin_amdgcn_global_load_lds(
                (const __attribute__((address_space(1))) void*)(
                    Abase + (size_t)t * 64 + (half ? halfA : 0) + goff[j]),
                (__attribute__((address_space(3))) void*)(sA[bufsel][half] + idx * 8),
                16, 0, 0);
        }
    };
    auto stageB = [&](int t, int half, int bufsel) {
#pragma unroll
        for (int j = 0; j < 2; j++) {
            int idx = j * 512 + tid;
            __builtin_amdgcn_global_load_lds(
                (const __attribute__((address_space(1))) void*)(
                    Bbase + (size_t)t * 64 + (half ? halfA : 0) + goff[j]),
                (__attribute__((address_space(3))) void*)(sB[bufsel][half] + idx * 8),
                16, 0, 0);
        }
    };
    auto rdA = [&](int buf, int i, int q) -> v8 {
        int row = i * 16 + l16;
        int byte = (row * 128 + q * 64 + quad * 16) ^ ((row & 7) << 4);
        return *(const v8*)((const char*)(sA[buf][wm]) + byte);
    };
    auto rdB = [&](int buf, int j, int q) -> v8 {
        int row = (wn & 1) * 64 + j * 16 + l16;
        int byte = (row * 128 + q * 64 + quad * 16) ^ ((row & 7) << 4);
        return *(const v8*)((const char*)(sB[buf][wn >> 1]) + byte);
    };

    floatx4 acc[8][4];
#pragma unroll
    for (int i = 0; i < 8; i++)
#pragma unroll
        for (int j = 0; j < 4; j++) acc[i][j] = (floatx4)0.0f;

    {
        int t1 = (1 < NT) ? 1 : 0;
        stageA(0, 0, 0); stageA(0, 1, 0);
        stageB(0, 0, 0); stageB(0, 1, 0);
        stageB(t1, 0, 1); stageB(t1, 1, 1);
        stageA(t1, 0, 1);
        asm volatile("s_waitcnt vmcnt(6)" ::: "memory");
        __builtin_amdgcn_s_barrier();
    }

    v8 a[8], b0[4], b1[4];
    for (int u = 0; u < NT; u += 2) {
#pragma unroll
        for (int half_it = 0; half_it < 2; half_it++) {
            const int t = u + half_it;
            const int buf = half_it;
            const int tA = (t + 1 < NT) ? t + 1 : NT - 1;
            const int tB = (t + 2 < NT) ? t + 2 : NT - 1;

            // ---- phase 1 ----
#pragma unroll
            for (int i = 0; i < 4; i++) { a[2 * i] = rdA(buf, i, 0); a[2 * i + 1] = rdA(buf, i, 1); }
#pragma unroll
            for (int j = 0; j < 2; j++) { b0[2 * j] = rdB(buf, j, 0); b0[2 * j + 1] = rdB(buf, j, 1); }
            stageA(tA, 1, buf ^ 1);
            __builtin_amdgcn_s_barrier();
            __builtin_amdgcn_s_setprio(1);
#pragma unroll
            for (int i = 0; i < 4; i++)
#pragma unroll
                for (int j = 0; j < 2; j++) {
                    acc[i][j] = mfma_any(a[2 * i], b0[2 * j], acc[i][j]);
                    acc[i][j] = mfma_any(a[2 * i + 1], b0[2 * j + 1], acc[i][j]);
                }
            __builtin_amdgcn_s_setprio(0);
            __builtin_amdgcn_s_barrier();

            // ---- phase 2 ----
#pragma unroll
            for (int j = 0; j < 2; j++) { b1[2 * j] = rdB(buf, 2 + j, 0); b1[2 * j + 1] = rdB(buf, 2 + j, 1); }
            __builtin_amdgcn_s_barrier();
            __builtin_amdgcn_s_setprio(1);
#pragma unroll
            for (int i = 0; i < 4; i++)
#pragma unroll
                for (int j = 0; j < 2; j++) {
                    acc[i][2 + j] = mfma_any(a[2 * i], b1[2 * j], acc[i][2 + j]);
                    acc[i][2 + j] = mfma_any(a[2 * i + 1], b1[2 * j + 1], acc[i][2 + j]);
                }
            __builtin_amdgcn_s_setprio(0);
            __builtin_amdgcn_s_barrier();

            // ---- phase 3 ----
#pragma unroll
            for (int i = 0; i < 4; i++) { a[2 * i] = rdA(buf, 4 + i, 0); a[2 * i + 1] = rdA(buf, 4 + i, 1); }
            stageB(tB, 0, buf);
            __builtin_amdgcn_s_barrier();
            __builtin_amdgcn_s_setprio(1);
#pragma unroll
            for (int i = 0; i < 4; i++)
#pragma unroll
                for (int j = 0; j < 2; j++) {
                    acc[4 + i][2 + j] = mfma_any(a[2 * i], b1[2 * j], acc[4 + i][2 + j]);
                    acc[4 + i][2 + j] = mfma_any(a[2 * i + 1], b1[2 * j + 1], acc[4 + i][2 + j]);
                }
            __builtin_amdgcn_s_setprio(0);
            __builtin_amdgcn_s_barrier();

            // ---- phase 4 ----
            stageB(tB, 1, buf);
            stageA(tB, 0, buf);
            asm volatile("s_waitcnt vmcnt(6)" ::: "memory");
            __builtin_amdgcn_s_barrier();
            __builtin_amdgcn_s_setprio(1);
#pragma unroll
            for (int i = 0; i < 4; i++)
#pragma unroll
                for (int j = 0; j < 2; j++) {
                    acc[4 + i][j] = mfma_any(a[2 * i], b0[2 * j], acc[4 + i][j]);
                    acc[4 + i][j] = mfma_any(a[2 * i + 1], b0[2 * j + 1], acc[4 + i][j]);
                }
            __builtin_amdgcn_s_setprio(0);
            __builtin_amdgcn_s_barrier();
        }
    }

    // epilogue
#pragma unroll
    for (int mf = 0; mf < 8; mf++)
#pragma unroll
        for (int nf = 0; nf < 4; nf++) {
            int col = n0 + wn * 64 + nf * 16 + l16;
            float badd = 0.0f;
            if (HAS_BIAS) {
                badd = bias1[col];
                if (bias2) badd += bias2[col];
            }
#pragma unroll
            for (int r = 0; r < 4; r++) {
                int row = m0 + wm * 128 + mf * 16 + quad * 4 + r;
                float v = acc[mf][nf][r];
                if (HAS_BIAS) v = (v + badd) * scale;
                C[(size_t)row * ldc + col] = (TO)v;
            }
        }
}

// ---------------------------------------------------------------------------
// m97-style GEMM (kept for fallback paths)
// ---------------------------------------------------------------------------
template <typename TI, typename TO, bool HAS_BIAS>
__global__ __launch_bounds__(256) void gemm128(
    const TI* __restrict__ A, const TI* __restrict__ B, TO* __restrict__ C,
    int K, int ldc, size_t strideA, size_t strideB, size_t strideC,
    const float* __restrict__ bias1, const float* __restrict__ bias2, float scale)
{
    using v8 = typename vec8_of<TI>::type;
    __shared__ TI sA[2 * 128 * 32];
    __shared__ TI sB[2 * 128 * 32];
    A += (size_t)blockIdx.z * strideA;
    B += (size_t)blockIdx.z * strideB;
    C += (size_t)blockIdx.z * strideC;

    const int tid = threadIdx.x;
    const int wave = tid >> 6, lane = tid & 63, quad = lane >> 4, l16 = lane & 15;
    const int m0 = blockIdx.x * 128, n0 = blockIdx.y * 128;
    const int wr = (wave >> 1) * 64, wc = (wave & 1) * 64;

    floatx4 acc[4][4];
#pragma unroll
    for (int i = 0; i < 4; i++)
#pragma unroll
        for (int j = 0; j < 4; j++) acc[i][j] = (floatx4)0.0f;

    for (int k0 = 0; k0 < K; k0 += 64) {
#pragma unroll
        for (int s = 0; s < 2; s++) {
#pragma unroll
            for (int j = 0; j < 2; j++) {
                int idx = j * 256 + tid;
                int r = idx >> 2, c = (idx & 3) * 8;
                __builtin_amdgcn_global_load_lds(
                    (const __attribute__((address_space(1))) void*)(A + (size_t)(m0 + r) * K + k0 + s * 32 + c),
                    (__attribute__((address_space(3))) void*)(sA + s * 4096 + idx * 8), 16, 0, 0);
                __builtin_amdgcn_global_load_lds(
                    (const __attribute__((address_space(1))) void*)(B + (size_t)(n0 + r) * K + k0 + s * 32 + c),
                    (__attribute__((address_space(3))) void*)(sB + s * 4096 + idx * 8), 16, 0, 0);
            }
        }
        __syncthreads();
#pragma unroll
        for (int s = 0; s < 2; s++) {
            v8 af[4], bfv[4];
#pragma unroll
            for (int i = 0; i < 4; i++) {
                af[i]  = *(const v8*)&sA[s * 4096 + (wr + i * 16 + l16) * 32 + quad * 8];
                bfv[i] = *(const v8*)&sB[s * 4096 + (wc + i * 16 + l16) * 32 + quad * 8];
            }
#pragma unroll
            for (int mf = 0; mf < 4; mf++)
#pragma unroll
                for (int nf = 0; nf < 4; nf++)
                    acc[mf][nf] = mfma_any(af[mf], bfv[nf], acc[mf][nf]);
        }
        __syncthreads();
    }

#pragma unroll
    for (int mf = 0; mf < 4; mf++)
#pragma unroll
        for (int nf = 0; nf < 4; nf++) {
            int col = n0 + wc + nf * 16 + l16;
            float badd = 0.0f;
            if (HAS_BIAS) {
                badd = bias1[col];
                if (bias2) badd += bias2[col];
            }
#pragma unroll
            for (int r = 0; r < 4; r++) {
                int row = m0 + wr + mf * 16 + quad * 4 + r;
                float v = acc[mf][nf][r];
                if (HAS_BIAS) v = (v + badd) * scale;
                C[(size_t)row * ldc + col] = (TO)v;
            }
        }
}

// ---------------------------------------------------------------------------
// transposes: vb [b][s][d] -> vtb [b][d][s]
// round-11: vectorized 64x64-tile version (16B loads + 16B stores via LDS).
// Load: 512 chunks of 8 bf16 per tile, 2/thread, fully coalesced.
// Store: build f16x8 from transposed LDS gather ([64][72] pad breaks the
// power-of-2 stride), fully coalesced 16B writes.
// ---------------------------------------------------------------------------
__global__ __launch_bounds__(256) void transpose_v_f16_64(
    const bf16* __restrict__ vb, f16* __restrict__ vtb)
{
    __shared__ bf16 tile[64][72];
    const int b = blockIdx.z;
    const int s0 = blockIdx.x * 64, d0 = blockIdx.y * 64;
    const int tid = threadIdx.x;

    // load: chunk idx = j*256+tid -> row = idx>>3 (0..63), col8 = (idx&7)*8
#pragma unroll
    for (int j = 0; j < 2; j++) {
        int idx = j * 256 + tid;
        int r = idx >> 3, c = (idx & 7) * 8;
        *(bf16x8*)&tile[r][c] =
            *(const bf16x8*)(vb + ((size_t)b * S_ + s0 + r) * D_ + d0 + c);
    }
    __syncthreads();

    // store: chunk idx = j*256+tid -> out-row d = idx>>3 (0..63),
    // out-col s-chunk = (idx&7)*8; gather 8 rows of column d from LDS.
#pragma unroll
    for (int j = 0; j < 2; j++) {
        int idx = j * 256 + tid;
        int d = idx >> 3, c = (idx & 7) * 8;
        f16x8 o;
#pragma unroll
        for (int e = 0; e < 8; e++) o[e] = (f16)(float)tile[c + e][d];
        *(f16x8*)(vtb + ((size_t)b * D_ + d0 + d) * S_ + s0 + c) = o;
    }
}

// bf16 variant for the flash fallback path
__global__ __launch_bounds__(256) void transpose_v_64(
    const bf16* __restrict__ vb, bf16* __restrict__ vtb)
{
    __shared__ bf16 tile[64][72];
    const int b = blockIdx.z;
    const int s0 = blockIdx.x * 64, d0 = blockIdx.y * 64;
    const int tid = threadIdx.x;
#pragma unroll
    for (int j = 0; j < 2; j++) {
        int idx = j * 256 + tid;
        int r = idx >> 3, c = (idx & 7) * 8;
        *(bf16x8*)&tile[r][c] =
            *(const bf16x8*)(vb + ((size_t)b * S_ + s0 + r) * D_ + d0 + c);
    }
    __syncthreads();
#pragma unroll
    for (int j = 0; j < 2; j++) {
        int idx = j * 256 + tid;
        int d = idx >> 3, c = (idx & 7) * 8;
        bf16x8 o;
#pragma unroll
        for (int e = 0; e < 8; e++) o[e] = tile[c + e][d];
        *(bf16x8*)(vtb + ((size_t)b * D_ + d0 + d) * S_ + s0 + c) = o;
    }
}

// ---------------------------------------------------------------------------
// softmax over one 4096-row of f16 scores, in place (normalized f16 out)
// ---------------------------------------------------------------------------
__global__ __launch_bounds__(256) void softmax_inplace_f16(f16* __restrict__ Sc)
{
    f16* row = Sc + (size_t)blockIdx.x * S_;
    const int tid = threadIdx.x, wave = tid >> 6, lane = tid & 63;
    __shared__ float redm[4], redl[4];

    f16x8 a = *(const f16x8*)(row + tid * 16);
    f16x8 b = *(const f16x8*)(row + tid * 16 + 8);
    float v[16];
#pragma unroll
    for (int j = 0; j < 8; j++) { v[j] = (float)a[j]; v[8 + j] = (float)b[j]; }

    float m = -1e30f;
#pragma unroll
    for (int j = 0; j < 16; j++) m = fmaxf(m, v[j]);
#pragma unroll
    for (int off = 32; off; off >>= 1) m = fmaxf(m, __shfl_xor(m, off));
    if (lane == 0) redm[wave] = m;
    __syncthreads();
    m = fmaxf(fmaxf(redm[0], redm[1]), fmaxf(redm[2], redm[3]));

    float s = 0.0f;
#pragma unroll
    for (int j = 0; j < 16; j++) { v[j] = __expf(v[j] - m); s += v[j]; }
#pragma unroll
    for (int off = 32; off; off >>= 1) s += __shfl_xor(s, off);
    if (lane == 0) redl[wave] = s;
    __syncthreads();
    s = redl[0] + redl[1] + redl[2] + redl[3];
    float inv = 1.0f / s;

#pragma unroll
    for (int j = 0; j < 8; j++) { a[j] = (f16)(v[j] * inv); b[j] = (f16)(v[8 + j] * inv); }
    *(f16x8*)(row + tid * 16) = a;
    *(f16x8*)(row + tid * 16 + 8) = b;
}

// ---------------------------------------------------------------------------
// softmax over one fp32 score row -> normalized fp16 (per-batch fallback)
// ---------------------------------------------------------------------------
__global__ __launch_bounds__(256) void softmax_row(
    const float* __restrict__ Sc, f16* __restrict__ P)
{
    const int q = blockIdx.x;
    const float* row = Sc + (size_t)q * S_;
    f16* prow = P + (size_t)q * S_;
    const int tid = threadIdx.x, wave = tid >> 6, lane = tid & 63;

    float4 v[4];
#pragma unroll
    for (int i = 0; i < 4; i++) v[i] = *(const float4*)(row + tid * 16 + i * 4);

    float m = -1e30f;
#pragma unroll
    for (int i = 0; i < 4; i++)
        m = fmaxf(m, fmaxf(fmaxf(v[i].x, v[i].y), fmaxf(v[i].z, v[i].w)));
#pragma unroll
    for (int off = 32; off; off >>= 1) m = fmaxf(m, __shfl_xor(m, off));
    __shared__ float redm[4], redl[4];
    if (lane == 0) redm[wave] = m;
    __syncthreads();
    m = fmaxf(fmaxf(redm[0], redm[1]), fmaxf(redm[2], redm[3]));

    float p[16];
    float s = 0.0f;
#pragma unroll
    for (int i = 0; i < 4; i++) {
        p[i * 4 + 0] = __expf(v[i].x - m);
        p[i * 4 + 1] = __expf(v[i].y - m);
        p[i * 4 + 2] = __expf(v[i].z - m);
        p[i * 4 + 3] = __expf(v[i].w - m);
        s += p[i * 4] + p[i * 4 + 1] + p[i * 4 + 2] + p[i * 4 + 3];
    }
#pragma unroll
    for (int off = 32; off; off >>= 1) s += __shfl_xor(s, off);
    if (lane == 0) redl[wave] = s;
    __syncthreads();
    s = redl[0] + redl[1] + redl[2] + redl[3];
    float inv = 1.0f / s;

    f16x8 o0, o1;
#pragma unroll
    for (int j = 0; j < 8; j++) {
        o0[j] = (f16)(p[j] * inv);
        o1[j] = (f16)(p[8 + j] * inv);
    }
    *(f16x8*)(prow + tid * 16) = o0;
    *(f16x8*)(prow + tid * 16 + 8) = o1;
}

// ---------------------------------------------------------------------------
// legacy fp32-input proj (flash fallback only)
// ---------------------------------------------------------------------------
#define SSTR 40
__global__ __launch_bounds__(256) void proj_gemm(
    const float* __restrict__ A, const float* __restrict__ W,
    const float* __restrict__ bias1, const float* __restrict__ bias2,
    bf16* __restrict__ C, float scale)
{
    __shared__ bf16 sA[64 * SSTR];
    __shared__ bf16 sB[64 * SSTR];
    const int tid = threadIdx.x;
    const int wave = tid >> 6, lane = tid & 63, quad = lane >> 4, l16 = lane & 15;
    const int m0 = blockIdx.x * 64, n0 = blockIdx.y * 64;
    const int wr = (wave >> 1) * 32, wc = (wave & 1) * 32;
    const int lr = tid >> 2;
    const int lc = (tid & 3) * 8;

    floatx4 acc[2][2];
#pragma unroll
    for (int i = 0; i < 2; i++)
#pragma unroll
        for (int j = 0; j < 2; j++) acc[i][j] = (floatx4)0.0f;

    for (int k0 = 0; k0 < 1024; k0 += 32) {
        const float* ga = A + (size_t)(m0 + lr) * 1024 + k0 + lc;
        const float* gw = W + (size_t)(n0 + lr) * 1024 + k0 + lc;
        float4 a0 = *(const float4*)ga;
        float4 a1 = *(const float4*)(ga + 4);
        float4 w0 = *(const float4*)gw;
        float4 w1 = *(const float4*)(gw + 4);
        *(bf16x8*)&sA[lr * SSTR + lc] = cvt8(a0, a1);
        *(bf16x8*)&sB[lr * SSTR + lc] = cvt8(w0, w1);
        __syncthreads();
        bf16x8 af[2], bfv[2];
        af[0]  = *(bf16x8*)&sA[(wr + l16) * SSTR + quad * 8];
        af[1]  = *(bf16x8*)&sA[(wr + 16 + l16) * SSTR + quad * 8];
        bfv[0] = *(bf16x8*)&sB[(wc + l16) * SSTR + quad * 8];
        bfv[1] = *(bf16x8*)&sB[(wc + 16 + l16) * SSTR + quad * 8];
#pragma unroll
        for (int mf = 0; mf < 2; mf++)
#pragma unroll
            for (int nf = 0; nf < 2; nf++)
                acc[mf][nf] = mfma16(af[mf], bfv[nf], acc[mf][nf]);
        __syncthreads();
    }
#pragma unroll
    for (int mf = 0; mf < 2; mf++)
#pragma unroll
        for (int nf = 0; nf < 2; nf++) {
            int col = n0 + wc + nf * 16 + l16;
            float bsum = bias1[col] + (bias2 ? bias2[col] : 0.0f);
#pragma unroll
            for (int r = 0; r < 4; r++) {
                int row = m0 + wr + mf * 16 + quad * 4 + r;
                C[(size_t)row * 1024 + col] = (bf16)((acc[mf][nf][r] + bsum) * scale);
            }
        }
}

// ---------------------------------------------------------------------------
// flash fallback (only if ws < 192MB)
// ---------------------------------------------------------------------------
#define BR 32
#define TK 64
#define DC 256
__global__ __launch_bounds__(256, 2) void flash_attn(
    const bf16* __restrict__ qb, const bf16* __restrict__ vb,
    const bf16* __restrict__ vtb, float* __restrict__ out)
{
    __shared__ float sPart[4][32][65];
    __shared__ bf16 sP[32][72];
    __shared__ float sM[32], sL[32], sAlpha[32];

    const int tid = threadIdx.x;
    const int wave = tid >> 6, lane = tid & 63, quad = lane >> 4, l16 = lane & 15;
    const int b = blockIdx.y, q0 = blockIdx.x * BR;

    bf16x8 qf[2][8];
#pragma unroll
    for (int mf = 0; mf < 2; mf++)
#pragma unroll
        for (int ks = 0; ks < 8; ks++) {
            int row = q0 + mf * 16 + l16;
            int col = wave * DC + ks * 32 + quad * 8;
            qf[mf][ks] = *(const bf16x8*)(qb + ((size_t)b * S_ + row) * D_ + col);
        }

    floatx4 o[2][16];
#pragma unroll
    for (int mf = 0; mf < 2; mf++)
#pragma unroll
        for (int nf = 0; nf < 16; nf++) o[mf][nf] = (floatx4)0.0f;

    if (tid < 32) { sM[tid] = -1e30f; sL[tid] = 0.0f; }
    __syncthreads();

    for (int kt = 0; kt < S_ / TK; kt++) {
        const int k0 = kt * TK;
        floatx4 sp[2][4];
#pragma unroll
        for (int mf = 0; mf < 2; mf++)
#pragma unroll
            for (int nf = 0; nf < 4; nf++) sp[mf][nf] = (floatx4)0.0f;
#pragma unroll
        for (int ks = 0; ks < 8; ks++) {
            int col = wave * DC + ks * 32 + quad * 8;
#pragma unroll
            for (int nf = 0; nf < 4; nf++) {
                int key = k0 + nf * 16 + l16;
                bf16x8 vf = *(const bf16x8*)(vb + ((size_t)b * S_ + key) * D_ + col);
                sp[0][nf] = mfma16(qf[0][ks], vf, sp[0][nf]);
                sp[1][nf] = mfma16(qf[1][ks], vf, sp[1][nf]);
            }
        }
#pragma unroll
        for (int mf = 0; mf < 2; mf++)
#pragma unroll
            for (int nf = 0; nf < 4; nf++)
#pragma unroll
                for (int r = 0; r < 4; r++)
                    sPart[wave][mf * 16 + quad * 4 + r][nf * 16 + l16] = sp[mf][nf][r];
        __syncthreads();

        {
            const int rr = tid >> 3, c0 = (tid & 7) * 8;
            float v[8];
            float mx = -1e30f;
#pragma unroll
            for (int j = 0; j < 8; j++) {
                v[j] = sPart[0][rr][c0 + j] + sPart[1][rr][c0 + j] +
                       sPart[2][rr][c0 + j] + sPart[3][rr][c0 + j];
                mx = fmaxf(mx, v[j]);
            }
            mx = fmaxf(mx, __shfl_xor(mx, 1));
            mx = fmaxf(mx, __shfl_xor(mx, 2));
            mx = fmaxf(mx, __shfl_xor(mx, 4));
            float m_old = sM[rr];
            float m_new = fmaxf(m_old, mx);
            float rsum = 0.0f;
#pragma unroll
            for (int j = 0; j < 8; j++) {
                float p = __expf(v[j] - m_new);
                sP[rr][c0 + j] = (bf16)p;
                rsum += p;
            }
            rsum += __shfl_xor(rsum, 1);
            rsum += __shfl_xor(rsum, 2);
            rsum += __shfl_xor(rsum, 4);
            if ((tid & 7) == 0) {
                float alpha = __expf(m_old - m_new);
                sAlpha[rr] = alpha;
                sM[rr] = m_new;
                sL[rr] = sL[rr] * alpha + rsum;
            }
        }
        __syncthreads();

        float al[2][4];
#pragma unroll
        for (int mf = 0; mf < 2; mf++)
#pragma unroll
            for (int r = 0; r < 4; r++) al[mf][r] = sAlpha[mf * 16 + quad * 4 + r];
#pragma unroll
        for (int mf = 0; mf < 2; mf++)
#pragma unroll
            for (int nf = 0; nf < 16; nf++)
#pragma unroll
                for (int r = 0; r < 4; r++) o[mf][nf][r] *= al[mf][r];

#pragma unroll
        for (int ks2 = 0; ks2 < 2; ks2++) {
            bf16x8 pA[2];
            pA[0] = *(bf16x8*)&sP[l16][ks2 * 32 + quad * 8];
            pA[1] = *(bf16x8*)&sP[16 + l16][ks2 * 32 + quad * 8];
            int key = k0 + ks2 * 32 + quad * 8;
#pragma unroll
            for (int nf = 0; nf < 16; nf++) {
                int d = wave * DC + nf * 16 + l16;
                bf16x8 vtf = *(const bf16x8*)(vtb + ((size_t)b * D_ + d) * S_ + key);
                o[0][nf] = mfma16(pA[0], vtf, o[0][nf]);
                o[1][nf] = mfma16(pA[1], vtf, o[1][nf]);
            }
        }
        __syncthreads();
    }

#pragma unroll
    for (int mf = 0; mf < 2; mf++) {
        float inv[4];
#pragma unroll
        for (int r = 0; r < 4; r++) inv[r] = 1.0f / sL[mf * 16 + quad * 4 + r];
#pragma unroll
        for (int nf = 0; nf < 16; nf++) {
            int d = wave * DC + nf * 16 + l16;
#pragma unroll
            for (int r = 0; r < 4; r++) {
                int row = q0 + mf * 16 + quad * 4 + r;
                out[((size_t)b * S_ + row) * D_ + d] = o[mf][nf][r] * inv[r];
            }
        }
    }
}

// ---------------------------------------------------------------------------
extern "C" void kernel_launch(void* const* d_in, const int* in_sizes, int n_in,
                              void* d_out, int out_size, void* d_ws, size_t ws_size,
                              hipStream_t stream) {
    const float* query = (const float*)d_in[0];
    const float* value = (const float*)d_in[1];
    const float* Wq    = (const float*)d_in[2];
    const float* bq    = (const float*)d_in[3];
    const float* qk_b  = (const float*)d_in[4];
    const float* Wv    = (const float*)d_in[5];
    const float* bv    = (const float*)d_in[6];
    float* out = (float*)d_out;

    const size_t SD = (size_t)S_ * D_;   // 4.19M elems
    const size_t SS = (size_t)S_ * S_;   // 16.8M elems
    const size_t MB = 1024 * 1024;

    char* w = (char*)d_ws;
    bf16* qb = (bf16*)w;                  // 32 MB (scale+bias folded)
    bf16* vb = (bf16*)(w + 32 * MB);      // 32 MB

    if (ws_size >= 224 * MB) {
        // ---- full batched path (round-6 verified 256^2 pipelined GEMMs) ----
        f16* vtb = (f16*)(w + 64 * MB);   // 32 MB [b][d][s]
        f16* Sc  = (f16*)(w + 96 * MB);   // 128 MB [b][q][k]; softmax in place
        bf16* qc  = (bf16*)(w + 96 * MB);   // 32 MB (aliases Sc until written)
        bf16* vc  = (bf16*)(w + 128 * MB);  // 32 MB
        bf16* wqc = (bf16*)(w + 160 * MB);  // 2 MB
        bf16* wvc = (bf16*)(w + 163 * MB);  // 2 MB

        cast2_f32_bf16<<<dim3((B_ * SD) / 2048, 1, 2), 256, 0, stream>>>(
            query, qc, value, vc);
        cast2_f32_bf16<<<dim3(((size_t)D_ * D_) / 2048, 1, 2), 256, 0, stream>>>(
            Wq, wqc, Wv, wvc);

        gemm256<bf16, bf16, true><<<dim3(256, 1, 1), 512, 0, stream>>>(
            qc, wqc, qb, D_, D_, 0, 0, 0, bq, qk_b, 0.125f, 4);
        gemm256<bf16, bf16, true><<<dim3(256, 1, 1), 512, 0, stream>>>(
            vc, wvc, vb, D_, D_, 0, 0, 0, bv, nullptr, 1.0f, 4);

        transpose_v_f16_64<<<dim3(S_ / 64, D_ / 64, B_), 256, 0, stream>>>(vb, vtb);

        gemm256<bf16, f16, false><<<dim3(256, 1, B_), 512, 0, stream>>>(
            qb, vb, Sc, D_, S_, SD, SD, SS, nullptr, nullptr, 1.0f, 16);

        softmax_inplace_f16<<<B_ * S_, 256, 0, stream>>>(Sc);

        gemm256<f16, float, false><<<dim3(64, 1, B_), 512, 0, stream>>>(
            Sc, vtb, out, S_, D_, SS, (size_t)D_ * S_, SD, nullptr, nullptr, 1.0f, 4);
    } else if (ws_size >= 192 * MB) {
        // ---- per-batch fallback (fp32 scores) ----
        f16*   vtb = (f16*)(w + 64 * MB);
        float* Sc  = (float*)(w + 96 * MB);
        f16*   Pn  = (f16*)(w + 160 * MB);
        bf16*  qc  = (bf16*)(w + 96 * MB);
        bf16*  vc  = (bf16*)(w + 128 * MB);
        bf16*  wqc = (bf16*)(w + 160 * MB);
        bf16*  wvc = (bf16*)(w + 163 * MB);

        cast2_f32_bf16<<<dim3((B_ * SD) / 2048, 1, 2), 256, 0, stream>>>(
            query, qc, value, vc);
        cast2_f32_bf16<<<dim3(((size_t)D_ * D_) / 2048, 1, 2), 256, 0, stream>>>(
            Wq, wqc, Wv, wvc);

        gemm128<bf16, bf16, true><<<dim3(128, 8, 1), 256, 0, stream>>>(
            qc, wqc, qb, D_, D_, 0, 0, 0, bq, qk_b, 0.125f);
        gemm128<bf16, bf16, true><<<dim3(128, 8, 1), 256, 0, stream>>>(
            vc, wvc, vb, D_, D_, 0, 0, 0, bv, nullptr, 1.0f);

        transpose_v_f16_64<<<dim3(S_ / 64, D_ / 64, B_), 256, 0, stream>>>(vb, vtb);

        for (int b = 0; b < B_; b++) {
            gemm128<bf16, float, false><<<dim3(32, 32, 1), 256, 0, stream>>>(
                qb + b * SD, vb + b * SD, Sc, D_, S_, 0, 0, 0, nullptr, nullptr, 1.0f);
            softmax_row<<<S_, 256, 0, stream>>>(Sc, Pn);
            gemm128<f16, float, false><<<dim3(32, 8, 1), 256, 0, stream>>>(
                Pn, vtb + (size_t)b * D_ * S_, out + b * SD, S_, D_,
                0, 0, 0, nullptr, nullptr, 1.0f);
        }
    } else {
        // ---- flash fallback (96 MB) ----
        bf16* vtb = (bf16*)(w + 64 * MB);
        dim3 pg(16384 / 64, 1024 / 64);
        proj_gemm<<<pg, 256, 0, stream>>>(query, Wq, bq, qk_b, qb, 0.125f);
        proj_gemm<<<pg, 256, 0, stream>>>(value, Wv, bv, nullptr, vb, 1.0f);
        transpose_v_64<<<dim3(S_ / 64, D_ / 64, B_), 256, 0, stream>>>(vb, vtb);
        flash_attn<<<dim3(S_ / BR, B_), 256, 0, stream>>>(qb, vb, vtb, out);
    }
}